// Round 3
// baseline (5818.272 us; speedup 1.0000x reference)
//
#include <hip/hip_runtime.h>
#include <math.h>

#define B_ 512
#define W_ 64
#define D_ 512
#define H_ 1024
#define NC_ 1024
#define K_ 8
#define C_ 64
#define BN_ 512
#define G3 (3*H_)

typedef unsigned short u16;
typedef __attribute__((ext_vector_type(8))) short bf16x8;
typedef __attribute__((ext_vector_type(4))) float f32x4;

__device__ __forceinline__ float bf_up(u16 h) { return __uint_as_float(((unsigned)h) << 16); }
__device__ __forceinline__ u16 bf_rn(float x) {
    unsigned u = __float_as_uint(x);
    return (u16)((u + 0x7FFFu + ((u >> 16) & 1u)) >> 16);
}

// convert 8 fp32 -> 8 (hi,lo) bf16 pairs, store as two 16B LDS writes
__device__ __forceinline__ void cvt_store8(u16* ph, u16* pl, float4 x, float4 y) {
    float v[8] = {x.x, x.y, x.z, x.w, y.x, y.y, y.z, y.w};
    union { u16 s[8]; uint4 u; } Hh, Ll;
    #pragma unroll
    for (int i = 0; i < 8; ++i) {
        unsigned ub = __float_as_uint(v[i]);
        u16 hi = (u16)(ub >> 16);                 // truncation
        float rem = v[i] - bf_up(hi);
        Hh.s[i] = hi;
        Ll.s[i] = bf_rn(rem);
    }
    *(uint4*)ph = Hh.u;
    *(uint4*)pl = Ll.u;
}

struct GArgs {
    const float* A;  long lda;       // fp32 A [M][K]
    const float* Bw;                 // fp32 B [N][K] (used when !BPRE)
    const u16* Bhi;  const u16* Blo; // pre-split B (used when BPRE)
    const float* bias;               // [N]
    float* C;  long ldc;
    int K;
};

// ---- MFMA hi/lo GEMM core: tile M64 x N128, BK=32, 256 threads (4 waves) ----
template<int ACT, int BPRE>
__device__ __forceinline__ void gemm_core(const GArgs g, int bx, int by, u16* lds)
{
    u16* Ah = lds;            // [64][40]
    u16* Al = lds + 2560;
    u16* Bh = lds + 5120;     // [128][40]
    u16* Bl = lds + 10240;
    const int tid = threadIdx.x;
    const int l = tid & 63, wv = tid >> 6;
    const int m0 = by * 64, n0 = bx * 128;
    const int sr = tid >> 2, sc = (tid & 3) * 8;

    const float* Ap = g.A + (long)(m0 + sr) * g.lda + sc;
    const float* Bp = 0; const u16 *Bph = 0, *Bpl = 0;
    if (BPRE) { Bph = g.Bhi + (long)(n0 + sr) * g.K + sc; Bpl = g.Blo + (long)(n0 + sr) * g.K + sc; }
    else      { Bp  = g.Bw  + (long)(n0 + sr) * g.K + sc; }
    const long Bstep = (long)64 * g.K;
    const int sA = sr * 40 + sc;
    const int sB1 = (sr + 64) * 40 + sc;

    f32x4 acc[4][2] = {};

    for (int k0 = 0; k0 < g.K; k0 += 32) {
        float4 a0 = *(const float4*)(Ap + k0);
        float4 a1 = *(const float4*)(Ap + k0 + 4);
        float4 b0, b1, b2, b3; uint4 h0, h1v, l0v, l1v;
        if (BPRE) {
            h0  = *(const uint4*)(Bph + k0);          l0v = *(const uint4*)(Bpl + k0);
            h1v = *(const uint4*)(Bph + Bstep + k0);  l1v = *(const uint4*)(Bpl + Bstep + k0);
        } else {
            b0 = *(const float4*)(Bp + k0);          b1 = *(const float4*)(Bp + k0 + 4);
            b2 = *(const float4*)(Bp + Bstep + k0);  b3 = *(const float4*)(Bp + Bstep + k0 + 4);
        }
        __syncthreads();
        cvt_store8(Ah + sA, Al + sA, a0, a1);
        if (BPRE) {
            *(uint4*)(Bh + sA) = h0;   *(uint4*)(Bl + sA) = l0v;
            *(uint4*)(Bh + sB1) = h1v; *(uint4*)(Bl + sB1) = l1v;
        } else {
            cvt_store8(Bh + sA, Bl + sA, b0, b1);
            cvt_store8(Bh + sB1, Bl + sB1, b2, b3);
        }
        __syncthreads();

        const int fr = (l & 15) * 40 + (l >> 4) * 8;
        bf16x8 ah[4], al[4], bh[2], bl[2];
        #pragma unroll
        for (int mt = 0; mt < 4; ++mt) {
            ah[mt] = *(const bf16x8*)(Ah + mt * 640 + fr);
            al[mt] = *(const bf16x8*)(Al + mt * 640 + fr);
        }
        #pragma unroll
        for (int nt = 0; nt < 2; ++nt) {
            bh[nt] = *(const bf16x8*)(Bh + (wv * 32 + nt * 16) * 40 + fr);
            bl[nt] = *(const bf16x8*)(Bl + (wv * 32 + nt * 16) * 40 + fr);
        }
        #pragma unroll
        for (int mt = 0; mt < 4; ++mt)
            #pragma unroll
            for (int nt = 0; nt < 2; ++nt) {
                acc[mt][nt] = __builtin_amdgcn_mfma_f32_16x16x32_bf16(ah[mt], bh[nt], acc[mt][nt], 0, 0, 0);
                acc[mt][nt] = __builtin_amdgcn_mfma_f32_16x16x32_bf16(ah[mt], bl[nt], acc[mt][nt], 0, 0, 0);
                acc[mt][nt] = __builtin_amdgcn_mfma_f32_16x16x32_bf16(al[mt], bh[nt], acc[mt][nt], 0, 0, 0);
            }
    }

    #pragma unroll
    for (int mt = 0; mt < 4; ++mt)
        #pragma unroll
        for (int nt = 0; nt < 2; ++nt) {
            int n = n0 + wv * 32 + nt * 16 + (l & 15);
            float bv = g.bias[n];
            #pragma unroll
            for (int r = 0; r < 4; ++r) {
                int m = m0 + mt * 16 + (l >> 4) * 4 + r;
                float v = acc[mt][nt][r] + bv;
                if (ACT == 1) v = v / (1.f + expf(-v));
                g.C[(long)m * g.ldc + n] = v;
            }
        }
}

template<int ACT, int BPRE>
__global__ __launch_bounds__(256)
void hilo_gemm(GArgs g) {
    __shared__ u16 lds[15360];
    gemm_core<ACT, BPRE>(g, blockIdx.x, blockIdx.y, lds);
}

// ---- fused GRU step: blocks [0,128): gh(3 gates)+update; blocks [128,320): gi(w+1) ----
struct StepArgs {
    const float* h_in;  float* h_out;
    const float* W_hh;  const u16* Whh_h; const u16* Whh_l;
    const float* gi;    // [B][G3], includes b_ih
    const float* b_hh;
    // gi-part (next step):
    const float* xw;    // x + (w+1)*D_, or nullptr on last step
    const float* W_ih;  const u16* Wih_h; const u16* Wih_l;
    const float* b_ih;
    float* gi_out;
};

template<int BPRE>
__global__ __launch_bounds__(256)
void gru_step(StepArgs s)
{
    __shared__ u16 lds[20480];
    const int id = blockIdx.x;
    if (id >= 128) {
        if (!s.xw) return;
        int id2 = id - 128;
        GArgs g;
        g.A = s.xw; g.lda = (long)W_ * D_;
        g.Bw = s.W_ih; g.Bhi = s.Wih_h; g.Blo = s.Wih_l;
        g.bias = s.b_ih; g.C = s.gi_out; g.ldc = G3; g.K = D_;
        gemm_core<0, BPRE>(g, id2 % 24, id2 / 24, lds);
        return;
    }
    // --- gh (3 gates) + GRU update ---
    u16* Ah = lds;              // [64][40]
    u16* Al = lds + 2560;
    u16* Bh = lds + 5120;       // 3 x [64][40]
    u16* Bl = lds + 12800;
    const int by = id >> 4, bx = id & 15;
    const int tid = threadIdx.x;
    const int l = tid & 63, wv = tid >> 6;
    const int m0 = by * 64, j0 = bx * 64;
    const int sr = tid >> 2, sc = (tid & 3) * 8;
    const int sA = sr * 40 + sc;

    const float* Ap = s.h_in + (long)(m0 + sr) * H_ + sc;

    f32x4 acc[3][4] = {};

    for (int k0 = 0; k0 < H_; k0 += 32) {
        float4 a0 = *(const float4*)(Ap + k0);
        float4 a1 = *(const float4*)(Ap + k0 + 4);
        uint4 bh4[3], bl4[3]; float4 bf0[3], bf1[3];
        #pragma unroll
        for (int g = 0; g < 3; ++g) {
            long row = (long)(g * H_ + j0 + sr);
            if (BPRE) {
                bh4[g] = *(const uint4*)(s.Whh_h + row * H_ + k0 + sc);
                bl4[g] = *(const uint4*)(s.Whh_l + row * H_ + k0 + sc);
            } else {
                bf0[g] = *(const float4*)(s.W_hh + row * H_ + k0 + sc);
                bf1[g] = *(const float4*)(s.W_hh + row * H_ + k0 + sc + 4);
            }
        }
        __syncthreads();
        cvt_store8(Ah + sA, Al + sA, a0, a1);
        #pragma unroll
        for (int g = 0; g < 3; ++g) {
            if (BPRE) {
                *(uint4*)(Bh + g * 2560 + sA) = bh4[g];
                *(uint4*)(Bl + g * 2560 + sA) = bl4[g];
            } else {
                cvt_store8(Bh + g * 2560 + sA, Bl + g * 2560 + sA, bf0[g], bf1[g]);
            }
        }
        __syncthreads();

        const int fr = (l & 15) * 40 + (l >> 4) * 8;
        bf16x8 ahf[4], alf[4], bhf[3], blf[3];
        #pragma unroll
        for (int mt = 0; mt < 4; ++mt) {
            ahf[mt] = *(const bf16x8*)(Ah + mt * 640 + fr);
            alf[mt] = *(const bf16x8*)(Al + mt * 640 + fr);
        }
        #pragma unroll
        for (int g = 0; g < 3; ++g) {
            bhf[g] = *(const bf16x8*)(Bh + g * 2560 + wv * 640 + fr);
            blf[g] = *(const bf16x8*)(Bl + g * 2560 + wv * 640 + fr);
        }
        #pragma unroll
        for (int g = 0; g < 3; ++g)
            #pragma unroll
            for (int mt = 0; mt < 4; ++mt) {
                acc[g][mt] = __builtin_amdgcn_mfma_f32_16x16x32_bf16(ahf[mt], bhf[g], acc[g][mt], 0, 0, 0);
                acc[g][mt] = __builtin_amdgcn_mfma_f32_16x16x32_bf16(ahf[mt], blf[g], acc[g][mt], 0, 0, 0);
                acc[g][mt] = __builtin_amdgcn_mfma_f32_16x16x32_bf16(alf[mt], bhf[g], acc[g][mt], 0, 0, 0);
            }
    }

    // epilogue: gates + pointwise GRU update, write h_out
    const int j = j0 + wv * 16 + (l & 15);
    const float bhr = s.b_hh[j], bhz = s.b_hh[H_ + j], bhn = s.b_hh[2 * H_ + j];
    #pragma unroll
    for (int mt = 0; mt < 4; ++mt) {
        #pragma unroll
        for (int r = 0; r < 4; ++r) {
            int m = m0 + mt * 16 + (l >> 4) * 4 + r;
            const float* gib = s.gi + (long)m * G3;
            float ir = gib[j], iz = gib[H_ + j], inn = gib[2 * H_ + j];
            float hr = acc[0][mt][r] + bhr;
            float hz = acc[1][mt][r] + bhz;
            float hn = acc[2][mt][r] + bhn;
            float rg = 1.f / (1.f + expf(-(ir + hr)));
            float zg = 1.f / (1.f + expf(-(iz + hz)));
            float ng = tanhf(inn + rg * hn);
            s.h_out[(long)m * H_ + j] = (1.f - zg) * ng + zg * s.h_in[(long)m * H_ + j];
        }
    }
}

// ---------------- fp32 -> hi/lo split (weights, once per launch) ----------------
__global__ __launch_bounds__(256)
void to_hilo(const float* __restrict__ src, u16* __restrict__ hi, u16* __restrict__ lo, long n8) {
    long i = (long)blockIdx.x * 256 + threadIdx.x;
    if (i >= n8) return;
    float4 a = ((const float4*)src)[2 * i];
    float4 b = ((const float4*)src)[2 * i + 1];
    union { u16 s[8]; uint4 u; } Hh, Ll;
    float v[8] = {a.x, a.y, a.z, a.w, b.x, b.y, b.z, b.w};
    #pragma unroll
    for (int j = 0; j < 8; ++j) {
        unsigned ub = __float_as_uint(v[j]);
        u16 h = (u16)(ub >> 16);
        Hh.s[j] = h;
        Ll.s[j] = bf_rn(v[j] - bf_up(h));
    }
    ((uint4*)hi)[i] = Hh.u;
    ((uint4*)lo)[i] = Ll.u;
}

// ---------------- emb row norms + zero loss slot ----------------
__global__ void emb_norm(const float* __restrict__ emb, float* __restrict__ e2,
                         float* __restrict__ loss_slot)
{
    int n = blockIdx.x * 256 + threadIdx.x;
    if (n == 0) *loss_slot = 0.f;
    if (n < NC_) {
        const float4* e4 = (const float4*)(emb + (long)n * C_);
        float s = 0.f;
        #pragma unroll
        for (int c = 0; c < 16; ++c) { float4 e = e4[c]; s += e.x*e.x + e.y*e.y + e.z*e.z + e.w*e.w; }
        e2[n] = s;
    }
}

// ---------------- VQ argmin: block = 32 queries, codes in 128-chunks ----------------
// thread: g = tid>>5 (4 queries), sI = tid&31 (codes sI + 32*jj, jj=0..3)
__global__ __launch_bounds__(256)
void vq_fused(const float* __restrict__ q, const float* __restrict__ emb,
              const float* __restrict__ e2, float* __restrict__ out_f,
              int* __restrict__ out_i)
{
    __shared__ float qs[32 * 66];
    __shared__ float es[128 * 66];
    const int blk = blockIdx.x, tid = threadIdx.x;
    {   // stage 32 queries (32x64) as float2
        const float2* src = ((const float2*)q) + (long)blk * 1024;
        #pragma unroll
        for (int f = tid; f < 1024; f += 256) {
            ((float2*)(qs + (f >> 5) * 66))[f & 31] = src[f];
        }
    }
    const int g = tid >> 5;
    const int sI = tid & 31;
    float best[4] = {3.4e38f, 3.4e38f, 3.4e38f, 3.4e38f};
    int   bi[4]   = {0, 0, 0, 0};

    for (int n0 = 0; n0 < NC_; n0 += 128) {
        const float2* esrc = ((const float2*)emb) + (long)n0 * 32;
        __syncthreads();   // previous chunk consumed
        #pragma unroll
        for (int f = tid; f < 4096; f += 256) {
            ((float2*)(es + (f >> 5) * 66))[f & 31] = esrc[f];
        }
        __syncthreads();
        float dot[4][4] = {};
        #pragma unroll 4
        for (int c = 0; c < 64; ++c) {
            float qv0 = qs[(g * 4 + 0) * 66 + c];
            float qv1 = qs[(g * 4 + 1) * 66 + c];
            float qv2 = qs[(g * 4 + 2) * 66 + c];
            float qv3 = qs[(g * 4 + 3) * 66 + c];
            #pragma unroll
            for (int jj = 0; jj < 4; ++jj) {
                float ev = es[(sI + 32 * jj) * 66 + c];
                dot[0][jj] += qv0 * ev;
                dot[1][jj] += qv1 * ev;
                dot[2][jj] += qv2 * ev;
                dot[3][jj] += qv3 * ev;
            }
        }
        #pragma unroll
        for (int jj = 0; jj < 4; ++jj) {
            int n = n0 + sI + 32 * jj;
            float e2v = e2[n];
            #pragma unroll
            for (int i = 0; i < 4; ++i) {
                float d = e2v - 2.f * dot[i][jj];
                if (d < best[i]) { best[i] = d; bi[i] = n; }
            }
        }
    }
    // reduce across the 32 lanes of each half-wave (sI bits = lane bits 0..4)
    #pragma unroll
    for (int m = 1; m <= 16; m <<= 1) {
        #pragma unroll
        for (int i = 0; i < 4; ++i) {
            float ov = __shfl_xor(best[i], m);
            int   oi = __shfl_xor(bi[i], m);
            if (ov < best[i] || (ov == best[i] && oi < bi[i])) { best[i] = ov; bi[i] = oi; }
        }
    }
    if (sI == 0) {
        #pragma unroll
        for (int i = 0; i < 4; ++i) {
            int bk = blk * 32 + g * 4 + i;
            out_f[bk] = (float)bi[i];
            out_i[bk] = bi[i];
        }
    }
}

// ---------------- gather quantized + loss ----------------
__global__ __launch_bounds__(256)
void gather_loss(const float* __restrict__ q, const float* __restrict__ emb,
                 const int* __restrict__ idx, float* __restrict__ quant_out,
                 float* __restrict__ narr_out, float* __restrict__ loss_slot)
{
    int i = blockIdx.x * 256 + threadIdx.x;  // B*K*C
    int bk = i >> 6;
    int c  = i & 63;
    float e  = emb[(long)idx[bk] * C_ + c];
    float qv = q[i];
    quant_out[i] = e;
    narr_out[i]  = e;
    float dsq = (qv - e) * (qv - e);
    __shared__ float red[256];
    red[threadIdx.x] = dsq;
    __syncthreads();
    for (int s = 128; s > 0; s >>= 1) {
        if (threadIdx.x < s) red[threadIdx.x] += red[threadIdx.x + s];
        __syncthreads();
    }
    if (threadIdx.x == 0)
        atomicAdd(loss_slot, red[0] * (1.25f / (float)(B_ * K_ * C_)));
}

// ---------------- build u_in = concat(last_world_state, narrator) ----------------
__global__ __launch_bounds__(256)
void build_uin(const float* __restrict__ x, const float* __restrict__ narr,
               float* __restrict__ uin)
{
    int i = blockIdx.x * 256 + threadIdx.x;  // B*1024
    int b = i >> 10;
    int j = i & 1023;
    uin[i] = (j < D_) ? x[(long)b * W_ * D_ + (long)(W_ - 1) * D_ + j]
                      : narr[(long)b * BN_ + (j - D_)];
}

__global__ __launch_bounds__(256)
void copy_f(const float* __restrict__ src, float* __restrict__ dst)
{
    int i = blockIdx.x * 256 + threadIdx.x;
    dst[i] = src[i];
}

extern "C" void kernel_launch(void* const* d_in, const int* in_sizes, int n_in,
                              void* d_out, int out_size, void* d_ws, size_t ws_size,
                              hipStream_t stream)
{
    (void)in_sizes; (void)n_in; (void)out_size;
    const float* x     = (const float*)d_in[0];
    const float* W_ih  = (const float*)d_in[1];
    const float* W_hh  = (const float*)d_in[2];
    const float* b_ih  = (const float*)d_in[3];
    const float* b_hh  = (const float*)d_in[4];
    const float* Wq    = (const float*)d_in[5];
    const float* bq    = (const float*)d_in[6];
    const float* emb   = (const float*)d_in[7];
    const float* uW1   = (const float*)d_in[8];
    const float* ub1   = (const float*)d_in[9];
    const float* uW2   = (const float*)d_in[10];
    const float* ub2   = (const float*)d_in[11];
    const float* pW1   = (const float*)d_in[12];
    const float* pb1   = (const float*)d_in[13];
    const float* pW2   = (const float*)d_in[14];
    const float* pb2   = (const float*)d_in[15];

    float* ws = (float*)d_ws;
    float* hA   = ws;                       // 524288
    float* giA  = ws + 524288;              // 1572864
    float* giB  = ws + 2097152;             // 1572864
    float* q    = ws + 3670016;             // 262144
    float* e2   = ws + 3932160;             // 1024
    int*   idxi = (int*)(ws + 3933184);     // 4096
    const long FLOAT_WORDS = 3937280;
    // tail-phase aliases (gi buffers dead after GRU loop)
    float* uin  = giB;                      // 524288
    float* mlph = giB + 524288;             // 524288
    float* t1   = giA;                      // 524288

    // optional pre-split weight region
    u16* wsu = (u16*)((char*)d_ws + FLOAT_WORDS * sizeof(float));
    u16* whh_h = wsu;            u16* whh_l = wsu + 3145728;
    u16* wih_h = wsu + 6291456;  u16* wih_l = wsu + 7864320;
    u16* wq_h  = wsu + 9437184;  u16* wq_l  = wsu + 9961472;
    u16* uw1_h = wsu + 10485760; u16* uw1_l = wsu + 11534336;
    u16* uw2_h = wsu + 12582912; u16* uw2_l = wsu + 13631488;
    u16* pw1_h = wsu + 14680064; u16* pw1_l = wsu + 15204352;
    u16* pw2_h = wsu + 15728640; u16* pw2_l = wsu + 16252928;
    const size_t NEED_BPRE = FLOAT_WORDS * sizeof(float) + (size_t)16777216 * 2;
    const bool bpre = ws_size >= NEED_BPRE;

    float* out = (float*)d_out;
    const long o_idx   = 0;
    const long o_quant = o_idx   + (long)B_ * K_;
    const long o_narr  = o_quant + (long)B_ * K_ * C_;
    const long o_unc   = o_narr  + (long)B_ * BN_;
    const long o_pred  = o_unc   + (long)B_ * H_;
    const long o_loss  = o_pred  + (long)B_ * BN_;
    const long o_lh    = o_loss  + 1;

    float* hB = out + o_unc;   // h ping-pong buffer; overwritten by uncertainty GEMM later
    float* hbuf[2] = { hA, hB };
    float* gibuf[2] = { giA, giB };

    hipMemsetAsync(hA, 0, (size_t)B_ * H_ * sizeof(float), stream);
    emb_norm<<<4, 256, 0, stream>>>(emb, e2, out + o_loss);

    if (bpre) {
        auto cvt = [&](const float* s, u16* hi, u16* lo, long n) {
            long n8 = n / 8;
            to_hilo<<<(int)((n8 + 255) / 256), 256, 0, stream>>>(s, hi, lo, n8);
        };
        cvt(W_hh, whh_h, whh_l, (long)G3 * H_);
        cvt(W_ih, wih_h, wih_l, (long)G3 * D_);
        cvt(Wq,   wq_h,  wq_l,  (long)BN_ * H_);
        cvt(uW1,  uw1_h, uw1_l, (long)H_ * (D_ + BN_));
        cvt(uW2,  uw2_h, uw2_l, (long)H_ * H_);
        cvt(pW1,  pw1_h, pw1_l, (long)H_ * BN_);
        cvt(pW2,  pw2_h, pw2_l, (long)BN_ * H_);
    }

    auto mkargs = [&](const float* A, long lda, const float* Bw, const u16* Bh, const u16* Bl,
                      const float* bias, float* C, long ldc, int K) {
        GArgs g; g.A = A; g.lda = lda; g.Bw = Bw; g.Bhi = Bh; g.Blo = Bl;
        g.bias = bias; g.C = C; g.ldc = ldc; g.K = K; return g;
    };

    // gi(0)
    {
        GArgs g0 = mkargs(x, (long)W_ * D_, W_ih, wih_h, wih_l, b_ih, gibuf[0], G3, D_);
        if (bpre) hilo_gemm<0, 1><<<dim3(G3 / 128, B_ / 64), 256, 0, stream>>>(g0);
        else      hilo_gemm<0, 0><<<dim3(G3 / 128, B_ / 64), 256, 0, stream>>>(g0);
    }

    // ---- fused GRU loop: one launch per step ----
    for (int w = 0; w < W_; ++w) {
        StepArgs s;
        s.h_in  = hbuf[w & 1];
        s.h_out = hbuf[(w + 1) & 1];
        s.W_hh = W_hh; s.Whh_h = whh_h; s.Whh_l = whh_l;
        s.gi = gibuf[w & 1];
        s.b_hh = b_hh;
        s.xw = (w + 1 < W_) ? (x + (long)(w + 1) * D_) : nullptr;
        s.W_ih = W_ih; s.Wih_h = wih_h; s.Wih_l = wih_l;
        s.b_ih = b_ih;
        s.gi_out = gibuf[(w + 1) & 1];
        if (bpre) gru_step<1><<<320, 256, 0, stream>>>(s);
        else      gru_step<0><<<320, 256, 0, stream>>>(s);
    }
    float* hfin = hbuf[0];   // after 64 steps, final h is back in hA

    auto gemm = [&](int act, GArgs g, int N, int M) {
        dim3 grid(N / 128, M / 64);
        if (bpre) {
            if (act == 1) hilo_gemm<1, 1><<<grid, 256, 0, stream>>>(g);
            else          hilo_gemm<0, 1><<<grid, 256, 0, stream>>>(g);
        } else {
            if (act == 1) hilo_gemm<1, 0><<<grid, 256, 0, stream>>>(g);
            else          hilo_gemm<0, 0><<<grid, 256, 0, stream>>>(g);
        }
    };

    // queries = h @ Wq^T + bq
    gemm(0, mkargs(hfin, H_, Wq, wq_h, wq_l, bq, q, BN_, H_), BN_, B_);

    vq_fused<<<B_ * K_ / 32, 256, 0, stream>>>(q, emb, e2, out + o_idx, idxi);
    gather_loss<<<(B_ * K_ * C_) / 256, 256, 0, stream>>>(
        q, emb, idxi, out + o_quant, out + o_narr, out + o_loss);

    build_uin<<<(B_ * (D_ + BN_)) / 256, 256, 0, stream>>>(x, out + o_narr, uin);

    // uncertainty = silu(u_in @ uW1^T + ub1) @ uW2^T + ub2   (overwrites hB region)
    gemm(1, mkargs(uin, D_ + BN_, uW1, uw1_h, uw1_l, ub1, mlph, H_, D_ + BN_), H_, B_);
    gemm(0, mkargs(mlph, H_, uW2, uw2_h, uw2_l, ub2, out + o_unc, H_, H_), H_, B_);

    // predicted = silu(narr @ pW1^T + pb1) @ pW2^T + pb2
    gemm(1, mkargs(out + o_narr, BN_, pW1, pw1_h, pw1_l, pb1, t1, H_, BN_), H_, B_);
    gemm(0, mkargs(t1, H_, pW2, pw2_h, pw2_l, pb2, out + o_pred, BN_, H_), BN_, B_);

    copy_f<<<(B_ * H_) / 256, 256, 0, stream>>>(hfin, out + o_lh);
}

// Round 4
// 5176.065 us; speedup vs baseline: 1.1241x; 1.1241x over previous
//
#include <hip/hip_runtime.h>
#include <math.h>

#define B_ 512
#define W_ 64
#define D_ 512
#define H_ 1024
#define NC_ 1024
#define K_ 8
#define C_ 64
#define BN_ 512
#define G3 (3*H_)

typedef unsigned short u16;
typedef __attribute__((ext_vector_type(8))) short bf16x8;
typedef __attribute__((ext_vector_type(4))) float f32x4;

__device__ __forceinline__ float bf_up(u16 h) { return __uint_as_float(((unsigned)h) << 16); }
__device__ __forceinline__ u16 bf_rn(float x) {
    unsigned u = __float_as_uint(x);
    return (u16)((u + 0x7FFFu + ((u >> 16) & 1u)) >> 16);
}

// convert 8 fp32 -> 8 (hi,lo) bf16 pairs, store as two 16B LDS writes
__device__ __forceinline__ void cvt_store8(u16* ph, u16* pl, float4 x, float4 y) {
    float v[8] = {x.x, x.y, x.z, x.w, y.x, y.y, y.z, y.w};
    union { u16 s[8]; uint4 u; } Hh, Ll;
    #pragma unroll
    for (int i = 0; i < 8; ++i) {
        unsigned ub = __float_as_uint(v[i]);
        u16 hi = (u16)(ub >> 16);                 // truncation
        float rem = v[i] - bf_up(hi);
        Hh.s[i] = hi;
        Ll.s[i] = bf_rn(rem);
    }
    *(uint4*)ph = Hh.u;
    *(uint4*)pl = Ll.u;
}

struct GArgs {
    const float* A;  long lda;       // fp32 A [M][K]
    const float* Bw;                 // fp32 B [N][K] (used when !BPRE)
    const u16* Bhi;  const u16* Blo; // pre-split B (used when BPRE)
    const float* bias;               // [N]
    float* C;  long ldc;
    int K;
};

// ---- MFMA hi/lo GEMM core: tile M64 x N64, BK=32, 256 threads (4 waves) ----
// wave wv handles n-strip [wv*16, wv*16+16): 4 m-frags
template<int ACT, int BPRE>
__device__ __forceinline__ void gemm_core64(const GArgs g, int bx, int by, u16* lds)
{
    u16* Ah = lds;            // [64][40]
    u16* Al = lds + 2560;
    u16* Bh = lds + 5120;     // [64][40]
    u16* Bl = lds + 7680;
    const int tid = threadIdx.x;
    const int l = tid & 63, wv = tid >> 6;
    const int m0 = by * 64, n0 = bx * 64;
    const int sr = tid >> 2, sc = (tid & 3) * 8;
    const int sA = sr * 40 + sc;

    const float* Ap = g.A + (long)(m0 + sr) * g.lda + sc;
    const float* Bp = 0; const u16 *Bph = 0, *Bpl = 0;
    if (BPRE) { Bph = g.Bhi + (long)(n0 + sr) * g.K + sc; Bpl = g.Blo + (long)(n0 + sr) * g.K + sc; }
    else      { Bp  = g.Bw  + (long)(n0 + sr) * g.K + sc; }

    f32x4 acc[4] = {};

    for (int k0 = 0; k0 < g.K; k0 += 32) {
        float4 a0 = *(const float4*)(Ap + k0);
        float4 a1 = *(const float4*)(Ap + k0 + 4);
        float4 b0, b1; uint4 h0, l0;
        if (BPRE) { h0 = *(const uint4*)(Bph + k0); l0 = *(const uint4*)(Bpl + k0); }
        else      { b0 = *(const float4*)(Bp + k0); b1 = *(const float4*)(Bp + k0 + 4); }
        __syncthreads();
        cvt_store8(Ah + sA, Al + sA, a0, a1);
        if (BPRE) { *(uint4*)(Bh + sA) = h0; *(uint4*)(Bl + sA) = l0; }
        else      { cvt_store8(Bh + sA, Bl + sA, b0, b1); }
        __syncthreads();

        const int fr = (l & 15) * 40 + (l >> 4) * 8;
        bf16x8 bh = *(const bf16x8*)(Bh + wv * 640 + fr);
        bf16x8 bl = *(const bf16x8*)(Bl + wv * 640 + fr);
        #pragma unroll
        for (int mt = 0; mt < 4; ++mt) {
            bf16x8 ah = *(const bf16x8*)(Ah + mt * 640 + fr);
            bf16x8 al = *(const bf16x8*)(Al + mt * 640 + fr);
            acc[mt] = __builtin_amdgcn_mfma_f32_16x16x32_bf16(ah, bh, acc[mt], 0, 0, 0);
            acc[mt] = __builtin_amdgcn_mfma_f32_16x16x32_bf16(ah, bl, acc[mt], 0, 0, 0);
            acc[mt] = __builtin_amdgcn_mfma_f32_16x16x32_bf16(al, bh, acc[mt], 0, 0, 0);
        }
    }

    const int n = n0 + wv * 16 + (l & 15);
    const float bv = g.bias[n];
    #pragma unroll
    for (int mt = 0; mt < 4; ++mt) {
        #pragma unroll
        for (int r = 0; r < 4; ++r) {
            int m = m0 + mt * 16 + (l >> 4) * 4 + r;
            float v = acc[mt][r] + bv;
            if (ACT == 1) v = v / (1.f + expf(-v));
            g.C[(long)m * g.ldc + n] = v;
        }
    }
}

template<int ACT, int BPRE>
__global__ __launch_bounds__(256)
void hilo_gemm64(GArgs g) {
    __shared__ u16 lds[10240];
    gemm_core64<ACT, BPRE>(g, blockIdx.x, blockIdx.y, lds);
}

// ---- fused GRU step ----
// blocks [0,256):   gh (32m x 64j x 3 gates, K=1024) + GRU update epilogue
// blocks [256,640): gi(w+1) as 64x64 tiles (48 n x 8 m)
struct StepArgs {
    const float* h_in;  float* h_out;
    const float* W_hh;  const u16* Whh_h; const u16* Whh_l;
    const float* gi;    // [B][G3], includes b_ih
    const float* b_hh;
    const float* xw;    // x + (w+1)*D_, or nullptr on last step
    const float* W_ih;  const u16* Wih_h; const u16* Wih_l;
    const float* b_ih;
    float* gi_out;
};

template<int BPRE>
__global__ __launch_bounds__(256)
void gru_step2(StepArgs s)
{
    __shared__ u16 lds[17920];
    const int id = blockIdx.x;
    const int tid = threadIdx.x;
    if (id >= 256) {
        if (!s.xw) return;
        int id2 = id - 256;
        GArgs g;
        g.A = s.xw; g.lda = (long)W_ * D_;
        g.Bw = s.W_ih; g.Bhi = s.Wih_h; g.Blo = s.Wih_l;
        g.bias = s.b_ih; g.C = s.gi_out; g.ldc = G3; g.K = D_;
        gemm_core64<0, BPRE>(g, id2 % 48, id2 / 48, lds);
        return;
    }
    // --- gh (3 gates, 32 m-rows) + GRU update ---
    u16* Ah = lds;               // [32][40]
    u16* Al = lds + 1280;
    u16* Bh = lds + 2560;        // [192][40]
    u16* Bl = lds + 10240;
    const int by = id >> 4, bx = id & 15;
    const int l = tid & 63, wv = tid >> 6;
    const int m0 = by * 32, j0 = bx * 64;
    const int sr = tid >> 2, sc = (tid & 3) * 8;   // B staging: 64 rows x 32 cols
    const int sA = sr * 40 + sc;

    const float* Ap = s.h_in + (long)(m0 + (tid >> 2)) * H_ + sc;  // threads < 128 only

    f32x4 acc[2][3] = {};

    for (int k0 = 0; k0 < H_; k0 += 32) {
        float4 a0, a1;
        if (tid < 128) {
            a0 = *(const float4*)(Ap + k0);
            a1 = *(const float4*)(Ap + k0 + 4);
        }
        uint4 bh4[3], bl4[3]; float4 bf0[3], bf1[3];
        #pragma unroll
        for (int g = 0; g < 3; ++g) {
            long row = (long)(g * H_ + j0 + sr);
            if (BPRE) {
                bh4[g] = *(const uint4*)(s.Whh_h + row * H_ + k0 + sc);
                bl4[g] = *(const uint4*)(s.Whh_l + row * H_ + k0 + sc);
            } else {
                bf0[g] = *(const float4*)(s.W_hh + row * H_ + k0 + sc);
                bf1[g] = *(const float4*)(s.W_hh + row * H_ + k0 + sc + 4);
            }
        }
        __syncthreads();
        if (tid < 128) cvt_store8(Ah + sA, Al + sA, a0, a1);
        #pragma unroll
        for (int g = 0; g < 3; ++g) {
            if (BPRE) {
                *(uint4*)(Bh + g * 2560 + sA) = bh4[g];
                *(uint4*)(Bl + g * 2560 + sA) = bl4[g];
            } else {
                cvt_store8(Bh + g * 2560 + sA, Bl + g * 2560 + sA, bf0[g], bf1[g]);
            }
        }
        __syncthreads();

        const int fr = (l & 15) * 40 + (l >> 4) * 8;
        bf16x8 bhf[3], blf[3];
        #pragma unroll
        for (int g = 0; g < 3; ++g) {
            bhf[g] = *(const bf16x8*)(Bh + g * 2560 + wv * 640 + fr);
            blf[g] = *(const bf16x8*)(Bl + g * 2560 + wv * 640 + fr);
        }
        #pragma unroll
        for (int mt = 0; mt < 2; ++mt) {
            bf16x8 ah = *(const bf16x8*)(Ah + mt * 640 + fr);
            bf16x8 al = *(const bf16x8*)(Al + mt * 640 + fr);
            #pragma unroll
            for (int g = 0; g < 3; ++g) {
                acc[mt][g] = __builtin_amdgcn_mfma_f32_16x16x32_bf16(ah, bhf[g], acc[mt][g], 0, 0, 0);
                acc[mt][g] = __builtin_amdgcn_mfma_f32_16x16x32_bf16(ah, blf[g], acc[mt][g], 0, 0, 0);
                acc[mt][g] = __builtin_amdgcn_mfma_f32_16x16x32_bf16(al, bhf[g], acc[mt][g], 0, 0, 0);
            }
        }
    }

    // epilogue: gates + pointwise GRU update, write h_out
    const int j = j0 + wv * 16 + (l & 15);
    const float bhr = s.b_hh[j], bhz = s.b_hh[H_ + j], bhn = s.b_hh[2 * H_ + j];
    #pragma unroll
    for (int mt = 0; mt < 2; ++mt) {
        #pragma unroll
        for (int r = 0; r < 4; ++r) {
            int m = m0 + mt * 16 + (l >> 4) * 4 + r;
            const float* gib = s.gi + (long)m * G3;
            float ir = gib[j], iz = gib[H_ + j], inn = gib[2 * H_ + j];
            float hr = acc[mt][0][r] + bhr;
            float hz = acc[mt][1][r] + bhz;
            float hn = acc[mt][2][r] + bhn;
            float rg = 1.f / (1.f + expf(-(ir + hr)));
            float zg = 1.f / (1.f + expf(-(iz + hz)));
            float ng = tanhf(inn + rg * hn);
            s.h_out[(long)m * H_ + j] = (1.f - zg) * ng + zg * s.h_in[(long)m * H_ + j];
        }
    }
}

// ---------------- fp32 -> hi/lo split (weights, once per launch) ----------------
__global__ __launch_bounds__(256)
void to_hilo(const float* __restrict__ src, u16* __restrict__ hi, u16* __restrict__ lo, long n8) {
    long i = (long)blockIdx.x * 256 + threadIdx.x;
    if (i >= n8) return;
    float4 a = ((const float4*)src)[2 * i];
    float4 b = ((const float4*)src)[2 * i + 1];
    union { u16 s[8]; uint4 u; } Hh, Ll;
    float v[8] = {a.x, a.y, a.z, a.w, b.x, b.y, b.z, b.w};
    #pragma unroll
    for (int j = 0; j < 8; ++j) {
        unsigned ub = __float_as_uint(v[j]);
        u16 h = (u16)(ub >> 16);
        Hh.s[j] = h;
        Ll.s[j] = bf_rn(v[j] - bf_up(h));
    }
    ((uint4*)hi)[i] = Hh.u;
    ((uint4*)lo)[i] = Ll.u;
}

// ---------------- emb row norms + zero loss slot ----------------
__global__ void emb_norm(const float* __restrict__ emb, float* __restrict__ e2,
                         float* __restrict__ loss_slot)
{
    int n = blockIdx.x * 256 + threadIdx.x;
    if (n == 0) *loss_slot = 0.f;
    if (n < NC_) {
        const float4* e4 = (const float4*)(emb + (long)n * C_);
        float s = 0.f;
        #pragma unroll
        for (int c = 0; c < 16; ++c) { float4 e = e4[c]; s += e.x*e.x + e.y*e.y + e.z*e.z + e.w*e.w; }
        e2[n] = s;
    }
}

// ---------------- VQ argmin: block = 32 queries, codes in 128-chunks ----------------
__global__ __launch_bounds__(256)
void vq_fused(const float* __restrict__ q, const float* __restrict__ emb,
              const float* __restrict__ e2, float* __restrict__ out_f,
              int* __restrict__ out_i)
{
    __shared__ float qs[32 * 66];
    __shared__ float es[128 * 66];
    const int blk = blockIdx.x, tid = threadIdx.x;
    {   // stage 32 queries (32x64) as float2
        const float2* src = ((const float2*)q) + (long)blk * 1024;
        #pragma unroll
        for (int f = tid; f < 1024; f += 256) {
            ((float2*)(qs + (f >> 5) * 66))[f & 31] = src[f];
        }
    }
    const int g = tid >> 5;
    const int sI = tid & 31;
    float best[4] = {3.4e38f, 3.4e38f, 3.4e38f, 3.4e38f};
    int   bi[4]   = {0, 0, 0, 0};

    for (int n0 = 0; n0 < NC_; n0 += 128) {
        const float2* esrc = ((const float2*)emb) + (long)n0 * 32;
        __syncthreads();
        #pragma unroll
        for (int f = tid; f < 4096; f += 256) {
            ((float2*)(es + (f >> 5) * 66))[f & 31] = esrc[f];
        }
        __syncthreads();
        float dot[4][4] = {};
        #pragma unroll 4
        for (int c = 0; c < 64; ++c) {
            float qv0 = qs[(g * 4 + 0) * 66 + c];
            float qv1 = qs[(g * 4 + 1) * 66 + c];
            float qv2 = qs[(g * 4 + 2) * 66 + c];
            float qv3 = qs[(g * 4 + 3) * 66 + c];
            #pragma unroll
            for (int jj = 0; jj < 4; ++jj) {
                float ev = es[(sI + 32 * jj) * 66 + c];
                dot[0][jj] += qv0 * ev;
                dot[1][jj] += qv1 * ev;
                dot[2][jj] += qv2 * ev;
                dot[3][jj] += qv3 * ev;
            }
        }
        #pragma unroll
        for (int jj = 0; jj < 4; ++jj) {
            int n = n0 + sI + 32 * jj;
            float e2v = e2[n];
            #pragma unroll
            for (int i = 0; i < 4; ++i) {
                float d = e2v - 2.f * dot[i][jj];
                if (d < best[i]) { best[i] = d; bi[i] = n; }
            }
        }
    }
    #pragma unroll
    for (int m = 1; m <= 16; m <<= 1) {
        #pragma unroll
        for (int i = 0; i < 4; ++i) {
            float ov = __shfl_xor(best[i], m);
            int   oi = __shfl_xor(bi[i], m);
            if (ov < best[i] || (ov == best[i] && oi < bi[i])) { best[i] = ov; bi[i] = oi; }
        }
    }
    if (sI == 0) {
        #pragma unroll
        for (int i = 0; i < 4; ++i) {
            int bk = blk * 32 + g * 4 + i;
            out_f[bk] = (float)bi[i];
            out_i[bk] = bi[i];
        }
    }
}

// ---------------- gather quantized + loss ----------------
__global__ __launch_bounds__(256)
void gather_loss(const float* __restrict__ q, const float* __restrict__ emb,
                 const int* __restrict__ idx, float* __restrict__ quant_out,
                 float* __restrict__ narr_out, float* __restrict__ loss_slot)
{
    int i = blockIdx.x * 256 + threadIdx.x;  // B*K*C
    int bk = i >> 6;
    int c  = i & 63;
    float e  = emb[(long)idx[bk] * C_ + c];
    float qv = q[i];
    quant_out[i] = e;
    narr_out[i]  = e;
    float dsq = (qv - e) * (qv - e);
    __shared__ float red[256];
    red[threadIdx.x] = dsq;
    __syncthreads();
    for (int s = 128; s > 0; s >>= 1) {
        if (threadIdx.x < s) red[threadIdx.x] += red[threadIdx.x + s];
        __syncthreads();
    }
    if (threadIdx.x == 0)
        atomicAdd(loss_slot, red[0] * (1.25f / (float)(B_ * K_ * C_)));
}

// ---------------- build u_in = concat(last_world_state, narrator) ----------------
__global__ __launch_bounds__(256)
void build_uin(const float* __restrict__ x, const float* __restrict__ narr,
               float* __restrict__ uin)
{
    int i = blockIdx.x * 256 + threadIdx.x;  // B*1024
    int b = i >> 10;
    int j = i & 1023;
    uin[i] = (j < D_) ? x[(long)b * W_ * D_ + (long)(W_ - 1) * D_ + j]
                      : narr[(long)b * BN_ + (j - D_)];
}

__global__ __launch_bounds__(256)
void copy_f(const float* __restrict__ src, float* __restrict__ dst)
{
    int i = blockIdx.x * 256 + threadIdx.x;
    dst[i] = src[i];
}

extern "C" void kernel_launch(void* const* d_in, const int* in_sizes, int n_in,
                              void* d_out, int out_size, void* d_ws, size_t ws_size,
                              hipStream_t stream)
{
    (void)in_sizes; (void)n_in; (void)out_size;
    const float* x     = (const float*)d_in[0];
    const float* W_ih  = (const float*)d_in[1];
    const float* W_hh  = (const float*)d_in[2];
    const float* b_ih  = (const float*)d_in[3];
    const float* b_hh  = (const float*)d_in[4];
    const float* Wq    = (const float*)d_in[5];
    const float* bq    = (const float*)d_in[6];
    const float* emb   = (const float*)d_in[7];
    const float* uW1   = (const float*)d_in[8];
    const float* ub1   = (const float*)d_in[9];
    const float* uW2   = (const float*)d_in[10];
    const float* ub2   = (const float*)d_in[11];
    const float* pW1   = (const float*)d_in[12];
    const float* pb1   = (const float*)d_in[13];
    const float* pW2   = (const float*)d_in[14];
    const float* pb2   = (const float*)d_in[15];

    float* ws = (float*)d_ws;
    float* hA   = ws;                       // 524288
    float* giA  = ws + 524288;              // 1572864
    float* giB  = ws + 2097152;             // 1572864
    float* q    = ws + 3670016;             // 262144
    float* e2   = ws + 3932160;             // 1024
    int*   idxi = (int*)(ws + 3933184);     // 4096
    const long FLOAT_WORDS = 3937280;
    // tail-phase aliases (gi buffers dead after GRU loop)
    float* uin  = giB;                      // 524288
    float* mlph = giB + 524288;             // 524288
    float* t1   = giA;                      // 524288

    // pre-split weight region (bpre confirmed active on this harness: ws >= 49.3 MB)
    u16* wsu = (u16*)((char*)d_ws + FLOAT_WORDS * sizeof(float));
    u16* whh_h = wsu;            u16* whh_l = wsu + 3145728;
    u16* wih_h = wsu + 6291456;  u16* wih_l = wsu + 7864320;
    u16* wq_h  = wsu + 9437184;  u16* wq_l  = wsu + 9961472;
    u16* uw1_h = wsu + 10485760; u16* uw1_l = wsu + 11534336;
    u16* uw2_h = wsu + 12582912; u16* uw2_l = wsu + 13631488;
    u16* pw1_h = wsu + 14680064; u16* pw1_l = wsu + 15204352;
    u16* pw2_h = wsu + 15728640; u16* pw2_l = wsu + 16252928;
    const size_t NEED_BPRE = FLOAT_WORDS * sizeof(float) + (size_t)16777216 * 2;
    const bool bpre = ws_size >= NEED_BPRE;

    float* out = (float*)d_out;
    const long o_idx   = 0;
    const long o_quant = o_idx   + (long)B_ * K_;
    const long o_narr  = o_quant + (long)B_ * K_ * C_;
    const long o_unc   = o_narr  + (long)B_ * BN_;
    const long o_pred  = o_unc   + (long)B_ * H_;
    const long o_loss  = o_pred  + (long)B_ * BN_;
    const long o_lh    = o_loss  + 1;

    float* hB = out + o_unc;   // h ping-pong buffer; overwritten by uncertainty GEMM later
    float* hbuf[2] = { hA, hB };
    float* gibuf[2] = { giA, giB };

    hipMemsetAsync(hA, 0, (size_t)B_ * H_ * sizeof(float), stream);
    emb_norm<<<4, 256, 0, stream>>>(emb, e2, out + o_loss);

    if (bpre) {
        auto cvt = [&](const float* s, u16* hi, u16* lo, long n) {
            long n8 = n / 8;
            to_hilo<<<(int)((n8 + 255) / 256), 256, 0, stream>>>(s, hi, lo, n8);
        };
        cvt(W_hh, whh_h, whh_l, (long)G3 * H_);
        cvt(W_ih, wih_h, wih_l, (long)G3 * D_);
        cvt(Wq,   wq_h,  wq_l,  (long)BN_ * H_);
        cvt(uW1,  uw1_h, uw1_l, (long)H_ * (D_ + BN_));
        cvt(uW2,  uw2_h, uw2_l, (long)H_ * H_);
        cvt(pW1,  pw1_h, pw1_l, (long)H_ * BN_);
        cvt(pW2,  pw2_h, pw2_l, (long)BN_ * H_);
    }

    auto mkargs = [&](const float* A, long lda, const float* Bw, const u16* Bh, const u16* Bl,
                      const float* bias, float* C, long ldc, int K) {
        GArgs g; g.A = A; g.lda = lda; g.Bw = Bw; g.Bhi = Bh; g.Blo = Bl;
        g.bias = bias; g.C = C; g.ldc = ldc; g.K = K; return g;
    };

    // gi(0)
    {
        GArgs g0 = mkargs(x, (long)W_ * D_, W_ih, wih_h, wih_l, b_ih, gibuf[0], G3, D_);
        if (bpre) hilo_gemm64<0, 1><<<dim3(48, 8), 256, 0, stream>>>(g0);
        else      hilo_gemm64<0, 0><<<dim3(48, 8), 256, 0, stream>>>(g0);
    }

    // ---- fused GRU loop: one launch per step, 640 blocks ----
    for (int w = 0; w < W_; ++w) {
        StepArgs s;
        s.h_in  = hbuf[w & 1];
        s.h_out = hbuf[(w + 1) & 1];
        s.W_hh = W_hh; s.Whh_h = whh_h; s.Whh_l = whh_l;
        s.gi = gibuf[w & 1];
        s.b_hh = b_hh;
        s.xw = (w + 1 < W_) ? (x + (long)(w + 1) * D_) : nullptr;
        s.W_ih = W_ih; s.Wih_h = wih_h; s.Wih_l = wih_l;
        s.b_ih = b_ih;
        s.gi_out = gibuf[(w + 1) & 1];
        if (bpre) gru_step2<1><<<640, 256, 0, stream>>>(s);
        else      gru_step2<0><<<640, 256, 0, stream>>>(s);
    }
    float* hfin = hbuf[0];   // after 64 steps, final h is back in hA

    auto gemm = [&](int act, GArgs g, int N, int M) {
        dim3 grid(N / 64, M / 64);
        if (bpre) {
            if (act == 1) hilo_gemm64<1, 1><<<grid, 256, 0, stream>>>(g);
            else          hilo_gemm64<0, 1><<<grid, 256, 0, stream>>>(g);
        } else {
            if (act == 1) hilo_gemm64<1, 0><<<grid, 256, 0, stream>>>(g);
            else          hilo_gemm64<0, 0><<<grid, 256, 0, stream>>>(g);
        }
    };

    // queries = h @ Wq^T + bq
    gemm(0, mkargs(hfin, H_, Wq, wq_h, wq_l, bq, q, BN_, H_), BN_, B_);

    vq_fused<<<B_ * K_ / 32, 256, 0, stream>>>(q, emb, e2, out + o_idx, idxi);
    gather_loss<<<(B_ * K_ * C_) / 256, 256, 0, stream>>>(
        q, emb, idxi, out + o_quant, out + o_narr, out + o_loss);

    build_uin<<<(B_ * (D_ + BN_)) / 256, 256, 0, stream>>>(x, out + o_narr, uin);

    // uncertainty = silu(u_in @ uW1^T + ub1) @ uW2^T + ub2
    gemm(1, mkargs(uin, D_ + BN_, uW1, uw1_h, uw1_l, ub1, mlph, H_, D_ + BN_), H_, B_);
    gemm(0, mkargs(mlph, H_, uW2, uw2_h, uw2_l, ub2, out + o_unc, H_, H_), H_, B_);

    // predicted = silu(narr @ pW1^T + pb1) @ pW2^T + pb2
    gemm(1, mkargs(out + o_narr, BN_, pW1, pw1_h, pw1_l, pb1, t1, H_, BN_), H_, B_);
    gemm(0, mkargs(t1, H_, pW2, pw2_h, pw2_l, pb2, out + o_pred, BN_, H_), BN_, B_);

    copy_f<<<(B_ * H_) / 256, 256, 0, stream>>>(hfin, out + o_lh);
}

// Round 5
// 2084.230 us; speedup vs baseline: 2.7916x; 2.4834x over previous
//
#include <hip/hip_runtime.h>
#include <math.h>

#define B_ 512
#define W_ 64
#define D_ 512
#define H_ 1024
#define NC_ 1024
#define K_ 8
#define C_ 64
#define BN_ 512
#define G3 (3*H_)

typedef unsigned short u16;
typedef __attribute__((ext_vector_type(8))) short bf16x8;
typedef __attribute__((ext_vector_type(4))) float f32x4;

__device__ __forceinline__ float bf_up(u16 h) { return __uint_as_float(((unsigned)h) << 16); }
__device__ __forceinline__ u16 bf_rn(float x) {
    unsigned u = __float_as_uint(x);
    return (u16)((u + 0x7FFFu + ((u >> 16) & 1u)) >> 16);
}

__device__ __forceinline__ void cvt_store8(u16* ph, u16* pl, float4 x, float4 y) {
    float v[8] = {x.x, x.y, x.z, x.w, y.x, y.y, y.z, y.w};
    union { u16 s[8]; uint4 u; } Hh, Ll;
    #pragma unroll
    for (int i = 0; i < 8; ++i) {
        unsigned ub = __float_as_uint(v[i]);
        u16 hi = (u16)(ub >> 16);
        float rem = v[i] - bf_up(hi);
        Hh.s[i] = hi;
        Ll.s[i] = bf_rn(rem);
    }
    *(uint4*)ph = Hh.u;
    *(uint4*)pl = Ll.u;
}

struct GArgs {
    const float* A;  long lda;
    const float* Bw;
    const u16* Bhi;  const u16* Blo;
    const float* bias;
    float* C;  long ldc;
    int K;
};

// ---- generic hi/lo GEMM (used for gi(0) + tail GEMMs), M64xN64, BK=32 ----
template<int ACT, int BPRE>
__device__ __forceinline__ void gemm_core64(const GArgs g, int bx, int by, u16* lds)
{
    u16* Ah = lds;
    u16* Al = lds + 2560;
    u16* Bh = lds + 5120;
    u16* Bl = lds + 7680;
    const int tid = threadIdx.x;
    const int l = tid & 63, wv = tid >> 6;
    const int m0 = by * 64, n0 = bx * 64;
    const int sr = tid >> 2, sc = (tid & 3) * 8;
    const int sA = sr * 40 + sc;

    const float* Ap = g.A + (long)(m0 + sr) * g.lda + sc;
    const float* Bp = 0; const u16 *Bph = 0, *Bpl = 0;
    if (BPRE) { Bph = g.Bhi + (long)(n0 + sr) * g.K + sc; Bpl = g.Blo + (long)(n0 + sr) * g.K + sc; }
    else      { Bp  = g.Bw  + (long)(n0 + sr) * g.K + sc; }

    f32x4 acc[4] = {};

    for (int k0 = 0; k0 < g.K; k0 += 32) {
        float4 a0 = *(const float4*)(Ap + k0);
        float4 a1 = *(const float4*)(Ap + k0 + 4);
        float4 b0, b1; uint4 h0, l0;
        if (BPRE) { h0 = *(const uint4*)(Bph + k0); l0 = *(const uint4*)(Bpl + k0); }
        else      { b0 = *(const float4*)(Bp + k0); b1 = *(const float4*)(Bp + k0 + 4); }
        __syncthreads();
        cvt_store8(Ah + sA, Al + sA, a0, a1);
        if (BPRE) { *(uint4*)(Bh + sA) = h0; *(uint4*)(Bl + sA) = l0; }
        else      { cvt_store8(Bh + sA, Bl + sA, b0, b1); }
        __syncthreads();

        const int fr = (l & 15) * 40 + (l >> 4) * 8;
        bf16x8 bh = *(const bf16x8*)(Bh + wv * 640 + fr);
        bf16x8 bl = *(const bf16x8*)(Bl + wv * 640 + fr);
        #pragma unroll
        for (int mt = 0; mt < 4; ++mt) {
            bf16x8 ah = *(const bf16x8*)(Ah + mt * 640 + fr);
            bf16x8 al = *(const bf16x8*)(Al + mt * 640 + fr);
            acc[mt] = __builtin_amdgcn_mfma_f32_16x16x32_bf16(ah, bh, acc[mt], 0, 0, 0);
            acc[mt] = __builtin_amdgcn_mfma_f32_16x16x32_bf16(ah, bl, acc[mt], 0, 0, 0);
            acc[mt] = __builtin_amdgcn_mfma_f32_16x16x32_bf16(al, bh, acc[mt], 0, 0, 0);
        }
    }

    const int n = n0 + wv * 16 + (l & 15);
    const float bv = g.bias[n];
    #pragma unroll
    for (int mt = 0; mt < 4; ++mt) {
        #pragma unroll
        for (int r = 0; r < 4; ++r) {
            int m = m0 + mt * 16 + (l >> 4) * 4 + r;
            float v = acc[mt][r] + bv;
            if (ACT == 1) v = v / (1.f + expf(-v));
            g.C[(long)m * g.ldc + n] = v;
        }
    }
}

template<int ACT, int BPRE>
__global__ __launch_bounds__(256)
void hilo_gemm64(GArgs g) {
    __shared__ u16 lds[10240];
    gemm_core64<ACT, BPRE>(g, blockIdx.x, blockIdx.y, lds);
}

// =================== fast fused GRU step ===================
struct FStep {
    const u16* hAh; const u16* hAl;    // split h(w)  [512][1024]
    const float* h_in;                 // fp32 h(w)
    float* h_out;                      // fp32 h(w+1)
    u16* hOh; u16* hOl;                // split h(w+1)
    const u16* WPh; const u16* WPl;    // gate-permuted whh split [3072][1024]
    const float* b_hh;
    const float* gi_in;                // gi(w) [512][3072] (b_ih included)
    const u16* xh; const u16* xl;      // split x slice (w+1) [512][512]
    const u16* Wih; const u16* Wil;    // wih split [3072][512]
    const float* b_ih;
    float* gi_out;                     // gi(w+1)
    const float* xpack_src;            // x + (w+2)*D  (strided [B][W][D]) or null
    u16* xph; u16* xpl;                // split x slice (w+2)
    int do_gi;
};

// 64m x 96n tile, u16 pre-split operands, dbuf LDS, 1 barrier per k-chunk.
// waves: mh = wv>>1 (32m half), tt = wv&1 (48n half = one gate-triple for GH)
template<int NK, int EPI>   // EPI 0: GH + GRU update epilogue; 1: GI plain store
__device__ __forceinline__ void fused_gemm96(const FStep& f, int bx, int by, u16* lds)
{
    const int K = NK * 32;
    const int tid = threadIdx.x;
    const int l = tid & 63, wv = tid >> 6;
    const int mh = wv >> 1, tt = wv & 1;
    const int m0 = by * 64, n0 = bx * 96;

    const u16 *Agh, *Agl, *Bgh, *Bgl;
    if (EPI == 0) { Agh = f.hAh; Agl = f.hAl; Bgh = f.WPh; Bgl = f.WPl; }
    else          { Agh = f.xh;  Agl = f.xl;  Bgh = f.Wih; Bgl = f.Wil; }

    const int r4 = tid >> 2, c4 = (tid & 3) * 8, t2 = tid - 128;
    // 5 static 16B chunks per thread per buffer: Ah, Al, Bh(r0-63), Bh(r64-95)|Bl(r0-31), Bl(r32-95)
    const u16* p0 = Agh + (long)(m0 + r4) * K + c4;
    const u16* p1 = Agl + (long)(m0 + r4) * K + c4;
    const u16* p2 = Bgh + (long)(n0 + r4) * K + c4;
    const u16* p3 = (tid < 128) ? Bgh + (long)(n0 + 64 + r4) * K + c4
                                : Bgl + (long)(n0 + (t2 >> 2)) * K + (t2 & 3) * 8;
    const u16* p4 = Bgl + (long)(n0 + 32 + r4) * K + c4;
    const int o0 = r4 * 40 + c4;
    const int o1 = 2560 + o0;
    const int o2 = 5120 + o0;
    const int o3 = (tid < 128) ? 5120 + (64 + r4) * 40 + c4
                               : 8960 + (t2 >> 2) * 40 + (t2 & 3) * 8;
    const int o4 = 8960 + (32 + r4) * 40 + c4;

    uint4 st0, st1, st2, st3, st4;
    #define LOAD5(kc) { int ko = (kc) * 32; \
        st0 = *(const uint4*)(p0 + ko); st1 = *(const uint4*)(p1 + ko); \
        st2 = *(const uint4*)(p2 + ko); st3 = *(const uint4*)(p3 + ko); \
        st4 = *(const uint4*)(p4 + ko); }
    #define WRITE5(base) { u16* bb = (base); \
        *(uint4*)(bb + o0) = st0; *(uint4*)(bb + o1) = st1; \
        *(uint4*)(bb + o2) = st2; *(uint4*)(bb + o3) = st3; \
        *(uint4*)(bb + o4) = st4; }

    f32x4 acc[2][3] = {};
    const int fr = (l & 15) * 40 + (l >> 4) * 8;

    LOAD5(0);
    WRITE5(lds);
    for (int kc = 0; kc < NK; ++kc) {
        const bool more = (kc + 1 < NK);
        if (more) LOAD5(kc + 1);
        __syncthreads();
        u16* buf = lds + (kc & 1) * 12800;
        bf16x8 a_h[2], a_l[2], b_h[3], b_l[3];
        #pragma unroll
        for (int mt = 0; mt < 2; ++mt) {
            a_h[mt] = *(const bf16x8*)(buf + (mh * 32 + mt * 16) * 40 + fr);
            a_l[mt] = *(const bf16x8*)(buf + 2560 + (mh * 32 + mt * 16) * 40 + fr);
        }
        #pragma unroll
        for (int g = 0; g < 3; ++g) {
            b_h[g] = *(const bf16x8*)(buf + 5120 + (tt * 48 + g * 16) * 40 + fr);
            b_l[g] = *(const bf16x8*)(buf + 8960 + (tt * 48 + g * 16) * 40 + fr);
        }
        #pragma unroll
        for (int mt = 0; mt < 2; ++mt)
            #pragma unroll
            for (int g = 0; g < 3; ++g) {
                acc[mt][g] = __builtin_amdgcn_mfma_f32_16x16x32_bf16(a_h[mt], b_h[g], acc[mt][g], 0, 0, 0);
                acc[mt][g] = __builtin_amdgcn_mfma_f32_16x16x32_bf16(a_h[mt], b_l[g], acc[mt][g], 0, 0, 0);
                acc[mt][g] = __builtin_amdgcn_mfma_f32_16x16x32_bf16(a_l[mt], b_h[g], acc[mt][g], 0, 0, 0);
            }
        if (more) WRITE5(lds + ((kc + 1) & 1) * 12800);
    }
    #undef LOAD5
    #undef WRITE5

    if (EPI == 0) {
        // GRU update: wave tt owns gate-triple of j-group (bx*2 + tt)
        const int j = (bx * 2 + tt) * 16 + (l & 15);
        const float bhr = f.b_hh[j], bhz = f.b_hh[H_ + j], bhn = f.b_hh[2 * H_ + j];
        #pragma unroll
        for (int mt = 0; mt < 2; ++mt) {
            #pragma unroll
            for (int r = 0; r < 4; ++r) {
                int m = m0 + mh * 32 + mt * 16 + (l >> 4) * 4 + r;
                const float* gib = f.gi_in + (long)m * G3;
                float ir = gib[j], iz = gib[H_ + j], inn = gib[2 * H_ + j];
                float hr = acc[mt][0][r] + bhr;
                float hz = acc[mt][1][r] + bhz;
                float hn = acc[mt][2][r] + bhn;
                float rg = 1.f / (1.f + expf(-(ir + hr)));
                float zg = 1.f / (1.f + expf(-(iz + hz)));
                float ng = tanhf(inn + rg * hn);
                float hv = (1.f - zg) * ng + zg * f.h_in[(long)m * H_ + j];
                long oidx = (long)m * H_ + j;
                f.h_out[oidx] = hv;
                unsigned ub = __float_as_uint(hv);
                u16 hh = (u16)(ub >> 16);
                f.hOh[oidx] = hh;
                f.hOl[oidx] = bf_rn(hv - bf_up(hh));
            }
        }
    } else {
        #pragma unroll
        for (int g = 0; g < 3; ++g) {
            const int n = n0 + tt * 48 + g * 16 + (l & 15);
            const float bv = f.b_ih[n];
            #pragma unroll
            for (int mt = 0; mt < 2; ++mt) {
                #pragma unroll
                for (int r = 0; r < 4; ++r) {
                    int m = m0 + mh * 32 + mt * 16 + (l >> 4) * 4 + r;
                    f.gi_out[(long)m * G3 + n] = acc[mt][g][r] + bv;
                }
            }
        }
    }
}

__device__ __forceinline__ void pack_slice_dev(const float* src, u16* dh, u16* dl,
                                               int blk, int tid)
{
    #pragma unroll
    for (int it = 0; it < 16; ++it) {
        int e4 = blk * 4096 + it * 256 + tid;   // float4 index, 65536 total
        int b = e4 >> 7, dd = (e4 & 127) * 4;
        float4 v = *(const float4*)(src + (long)b * (W_ * D_) + dd);
        union { u16 s[4]; uint2 u; } Hh, Ll;
        float vv[4] = {v.x, v.y, v.z, v.w};
        #pragma unroll
        for (int i = 0; i < 4; ++i) {
            unsigned ub = __float_as_uint(vv[i]);
            u16 hi = (u16)(ub >> 16);
            Hh.s[i] = hi;
            Ll.s[i] = bf_rn(vv[i] - bf_up(hi));
        }
        long o = (long)b * D_ + dd;
        *(uint2*)(dh + o) = Hh.u;
        *(uint2*)(dl + o) = Ll.u;
    }
}

__global__ __launch_bounds__(256)
void gru_fused(FStep f)
{
    __shared__ u16 lds[25600];
    const int id = blockIdx.x;
    if (id < 256) {
        fused_gemm96<32, 0>(f, id & 31, id >> 5, lds);
    } else if (id < 512) {
        if (!f.do_gi) return;
        int id2 = id - 256;
        fused_gemm96<16, 1>(f, id2 & 31, id2 >> 5, lds);
    } else {
        if (!f.xpack_src) return;
        pack_slice_dev(f.xpack_src, f.xph, f.xpl, id - 512, threadIdx.x);
    }
}

__global__ __launch_bounds__(256)
void pack_x(const float* src, u16* dh, u16* dl)
{
    pack_slice_dev(src, dh, dl, blockIdx.x, threadIdx.x);
}

// ---------------- prep: fp32 -> hi/lo split ----------------
__global__ __launch_bounds__(256)
void to_hilo(const float* __restrict__ src, u16* __restrict__ hi, u16* __restrict__ lo, long n8) {
    long i = (long)blockIdx.x * 256 + threadIdx.x;
    if (i >= n8) return;
    float4 a = ((const float4*)src)[2 * i];
    float4 b = ((const float4*)src)[2 * i + 1];
    union { u16 s[8]; uint4 u; } Hh, Ll;
    float v[8] = {a.x, a.y, a.z, a.w, b.x, b.y, b.z, b.w};
    #pragma unroll
    for (int j = 0; j < 8; ++j) {
        unsigned ub = __float_as_uint(v[j]);
        u16 h = (u16)(ub >> 16);
        Hh.s[j] = h;
        Ll.s[j] = bf_rn(v[j] - bf_up(h));
    }
    ((uint4*)hi)[i] = Hh.u;
    ((uint4*)lo)[i] = Ll.u;
}

// whh with gate-interleaved row permutation: src row g*H+j -> dst row (j>>4)*48 + g*16 + (j&15)
__global__ __launch_bounds__(256)
void to_hilo_perm(const float* __restrict__ src, u16* __restrict__ hi, u16* __restrict__ lo)
{
    long i = (long)blockIdx.x * 256 + threadIdx.x;   // float4 index, 3072*256 total
    if (i >= (long)G3 * 256) return;
    int row = (int)(i >> 8);
    int c4 = (int)(i & 255) * 4;
    int g = row >> 10, j = row & 1023;
    int drow = (j >> 4) * 48 + g * 16 + (j & 15);
    float4 v = *(const float4*)(src + (long)row * H_ + c4);
    union { u16 s[4]; uint2 u; } Hh, Ll;
    float vv[4] = {v.x, v.y, v.z, v.w};
    #pragma unroll
    for (int t = 0; t < 4; ++t) {
        unsigned ub = __float_as_uint(vv[t]);
        u16 h = (u16)(ub >> 16);
        Hh.s[t] = h;
        Ll.s[t] = bf_rn(vv[t] - bf_up(h));
    }
    long o = (long)drow * H_ + c4;
    *(uint2*)(hi + o) = Hh.u;
    *(uint2*)(lo + o) = Ll.u;
}

// =================== legacy round-4 step kernel (fallback) ===================
struct StepArgs {
    const float* h_in;  float* h_out;
    const float* W_hh;  const u16* Whh_h; const u16* Whh_l;
    const float* gi;
    const float* b_hh;
    const float* xw;
    const float* W_ih;  const u16* Wih_h; const u16* Wih_l;
    const float* b_ih;
    float* gi_out;
};

template<int BPRE>
__global__ __launch_bounds__(256)
void gru_step2(StepArgs s)
{
    __shared__ u16 lds[17920];
    const int id = blockIdx.x;
    const int tid = threadIdx.x;
    if (id >= 256) {
        if (!s.xw) return;
        int id2 = id - 256;
        GArgs g;
        g.A = s.xw; g.lda = (long)W_ * D_;
        g.Bw = s.W_ih; g.Bhi = s.Wih_h; g.Blo = s.Wih_l;
        g.bias = s.b_ih; g.C = s.gi_out; g.ldc = G3; g.K = D_;
        gemm_core64<0, BPRE>(g, id2 % 48, id2 / 48, lds);
        return;
    }
    u16* Ah = lds;
    u16* Al = lds + 1280;
    u16* Bh = lds + 2560;
    u16* Bl = lds + 10240;
    const int by = id >> 4, bx = id & 15;
    const int l = tid & 63, wv = tid >> 6;
    const int m0 = by * 32, j0 = bx * 64;
    const int sr = tid >> 2, sc = (tid & 3) * 8;
    const int sA = sr * 40 + sc;

    const float* Ap = s.h_in + (long)(m0 + (tid >> 2)) * H_ + sc;

    f32x4 acc[2][3] = {};

    for (int k0 = 0; k0 < H_; k0 += 32) {
        float4 a0, a1;
        if (tid < 128) {
            a0 = *(const float4*)(Ap + k0);
            a1 = *(const float4*)(Ap + k0 + 4);
        }
        uint4 bh4[3], bl4[3]; float4 bf0[3], bf1[3];
        #pragma unroll
        for (int g = 0; g < 3; ++g) {
            long row = (long)(g * H_ + j0 + sr);
            if (BPRE) {
                bh4[g] = *(const uint4*)(s.Whh_h + row * H_ + k0 + sc);
                bl4[g] = *(const uint4*)(s.Whh_l + row * H_ + k0 + sc);
            } else {
                bf0[g] = *(const float4*)(s.W_hh + row * H_ + k0 + sc);
                bf1[g] = *(const float4*)(s.W_hh + row * H_ + k0 + sc + 4);
            }
        }
        __syncthreads();
        if (tid < 128) cvt_store8(Ah + sA, Al + sA, a0, a1);
        #pragma unroll
        for (int g = 0; g < 3; ++g) {
            if (BPRE) {
                *(uint4*)(Bh + g * 2560 + sA) = bh4[g];
                *(uint4*)(Bl + g * 2560 + sA) = bl4[g];
            } else {
                cvt_store8(Bh + g * 2560 + sA, Bl + g * 2560 + sA, bf0[g], bf1[g]);
            }
        }
        __syncthreads();

        const int fr = (l & 15) * 40 + (l >> 4) * 8;
        bf16x8 bhf[3], blf[3];
        #pragma unroll
        for (int g = 0; g < 3; ++g) {
            bhf[g] = *(const bf16x8*)(Bh + g * 2560 + wv * 640 + fr);
            blf[g] = *(const bf16x8*)(Bl + g * 2560 + wv * 640 + fr);
        }
        #pragma unroll
        for (int mt = 0; mt < 2; ++mt) {
            bf16x8 ah = *(const bf16x8*)(Ah + mt * 640 + fr);
            bf16x8 al = *(const bf16x8*)(Al + mt * 640 + fr);
            #pragma unroll
            for (int g = 0; g < 3; ++g) {
                acc[mt][g] = __builtin_amdgcn_mfma_f32_16x16x32_bf16(ah, bhf[g], acc[mt][g], 0, 0, 0);
                acc[mt][g] = __builtin_amdgcn_mfma_f32_16x16x32_bf16(ah, blf[g], acc[mt][g], 0, 0, 0);
                acc[mt][g] = __builtin_amdgcn_mfma_f32_16x16x32_bf16(al, bhf[g], acc[mt][g], 0, 0, 0);
            }
        }
    }

    const int j = j0 + wv * 16 + (l & 15);
    const float bhr = s.b_hh[j], bhz = s.b_hh[H_ + j], bhn = s.b_hh[2 * H_ + j];
    #pragma unroll
    for (int mt = 0; mt < 2; ++mt) {
        #pragma unroll
        for (int r = 0; r < 4; ++r) {
            int m = m0 + mt * 16 + (l >> 4) * 4 + r;
            const float* gib = s.gi + (long)m * G3;
            float ir = gib[j], iz = gib[H_ + j], inn = gib[2 * H_ + j];
            float hr = acc[mt][0][r] + bhr;
            float hz = acc[mt][1][r] + bhz;
            float hn = acc[mt][2][r] + bhn;
            float rg = 1.f / (1.f + expf(-(ir + hr)));
            float zg = 1.f / (1.f + expf(-(iz + hz)));
            float ng = tanhf(inn + rg * hn);
            s.h_out[(long)m * H_ + j] = (1.f - zg) * ng + zg * s.h_in[(long)m * H_ + j];
        }
    }
}

// ---------------- misc small kernels ----------------
__global__ void emb_norm(const float* __restrict__ emb, float* __restrict__ e2,
                         float* __restrict__ loss_slot)
{
    int n = blockIdx.x * 256 + threadIdx.x;
    if (n == 0) *loss_slot = 0.f;
    if (n < NC_) {
        const float4* e4 = (const float4*)(emb + (long)n * C_);
        float s = 0.f;
        #pragma unroll
        for (int c = 0; c < 16; ++c) { float4 e = e4[c]; s += e.x*e.x + e.y*e.y + e.z*e.z + e.w*e.w; }
        e2[n] = s;
    }
}

__global__ __launch_bounds__(256)
void vq_fused(const float* __restrict__ q, const float* __restrict__ emb,
              const float* __restrict__ e2, float* __restrict__ out_f,
              int* __restrict__ out_i)
{
    __shared__ float qs[32 * 66];
    __shared__ float es[128 * 66];
    const int blk = blockIdx.x, tid = threadIdx.x;
    {
        const float2* src = ((const float2*)q) + (long)blk * 1024;
        #pragma unroll
        for (int f = tid; f < 1024; f += 256) {
            ((float2*)(qs + (f >> 5) * 66))[f & 31] = src[f];
        }
    }
    const int g = tid >> 5;
    const int sI = tid & 31;
    float best[4] = {3.4e38f, 3.4e38f, 3.4e38f, 3.4e38f};
    int   bi[4]   = {0, 0, 0, 0};

    for (int n0 = 0; n0 < NC_; n0 += 128) {
        const float2* esrc = ((const float2*)emb) + (long)n0 * 32;
        __syncthreads();
        #pragma unroll
        for (int f = tid; f < 4096; f += 256) {
            ((float2*)(es + (f >> 5) * 66))[f & 31] = esrc[f];
        }
        __syncthreads();
        float dot[4][4] = {};
        #pragma unroll 4
        for (int c = 0; c < 64; ++c) {
            float qv0 = qs[(g * 4 + 0) * 66 + c];
            float qv1 = qs[(g * 4 + 1) * 66 + c];
            float qv2 = qs[(g * 4 + 2) * 66 + c];
            float qv3 = qs[(g * 4 + 3) * 66 + c];
            #pragma unroll
            for (int jj = 0; jj < 4; ++jj) {
                float ev = es[(sI + 32 * jj) * 66 + c];
                dot[0][jj] += qv0 * ev;
                dot[1][jj] += qv1 * ev;
                dot[2][jj] += qv2 * ev;
                dot[3][jj] += qv3 * ev;
            }
        }
        #pragma unroll
        for (int jj = 0; jj < 4; ++jj) {
            int n = n0 + sI + 32 * jj;
            float e2v = e2[n];
            #pragma unroll
            for (int i = 0; i < 4; ++i) {
                float d = e2v - 2.f * dot[i][jj];
                if (d < best[i]) { best[i] = d; bi[i] = n; }
            }
        }
    }
    #pragma unroll
    for (int m = 1; m <= 16; m <<= 1) {
        #pragma unroll
        for (int i = 0; i < 4; ++i) {
            float ov = __shfl_xor(best[i], m);
            int   oi = __shfl_xor(bi[i], m);
            if (ov < best[i] || (ov == best[i] && oi < bi[i])) { best[i] = ov; bi[i] = oi; }
        }
    }
    if (sI == 0) {
        #pragma unroll
        for (int i = 0; i < 4; ++i) {
            int bk = blk * 32 + g * 4 + i;
            out_f[bk] = (float)bi[i];
            out_i[bk] = bi[i];
        }
    }
}

__global__ __launch_bounds__(256)
void gather_loss(const float* __restrict__ q, const float* __restrict__ emb,
                 const int* __restrict__ idx, float* __restrict__ quant_out,
                 float* __restrict__ narr_out, float* __restrict__ loss_slot)
{
    int i = blockIdx.x * 256 + threadIdx.x;
    int bk = i >> 6;
    int c  = i & 63;
    float e  = emb[(long)idx[bk] * C_ + c];
    float qv = q[i];
    quant_out[i] = e;
    narr_out[i]  = e;
    float dsq = (qv - e) * (qv - e);
    __shared__ float red[256];
    red[threadIdx.x] = dsq;
    __syncthreads();
    for (int s = 128; s > 0; s >>= 1) {
        if (threadIdx.x < s) red[threadIdx.x] += red[threadIdx.x + s];
        __syncthreads();
    }
    if (threadIdx.x == 0)
        atomicAdd(loss_slot, red[0] * (1.25f / (float)(B_ * K_ * C_)));
}

__global__ __launch_bounds__(256)
void build_uin(const float* __restrict__ x, const float* __restrict__ narr,
               float* __restrict__ uin)
{
    int i = blockIdx.x * 256 + threadIdx.x;
    int b = i >> 10;
    int j = i & 1023;
    uin[i] = (j < D_) ? x[(long)b * W_ * D_ + (long)(W_ - 1) * D_ + j]
                      : narr[(long)b * BN_ + (j - D_)];
}

__global__ __launch_bounds__(256)
void copy_f(const float* __restrict__ src, float* __restrict__ dst)
{
    int i = blockIdx.x * 256 + threadIdx.x;
    dst[i] = src[i];
}

extern "C" void kernel_launch(void* const* d_in, const int* in_sizes, int n_in,
                              void* d_out, int out_size, void* d_ws, size_t ws_size,
                              hipStream_t stream)
{
    (void)in_sizes; (void)n_in; (void)out_size;
    const float* x     = (const float*)d_in[0];
    const float* W_ih  = (const float*)d_in[1];
    const float* W_hh  = (const float*)d_in[2];
    const float* b_ih  = (const float*)d_in[3];
    const float* b_hh  = (const float*)d_in[4];
    const float* Wq    = (const float*)d_in[5];
    const float* bq    = (const float*)d_in[6];
    const float* emb   = (const float*)d_in[7];
    const float* uW1   = (const float*)d_in[8];
    const float* ub1   = (const float*)d_in[9];
    const float* uW2   = (const float*)d_in[10];
    const float* ub2   = (const float*)d_in[11];
    const float* pW1   = (const float*)d_in[12];
    const float* pb1   = (const float*)d_in[13];
    const float* pW2   = (const float*)d_in[14];
    const float* pb2   = (const float*)d_in[15];

    float* ws = (float*)d_ws;
    float* hA   = ws;                       // 524288
    float* giA  = ws + 524288;              // 1572864
    float* giB  = ws + 2097152;             // 1572864
    float* q    = ws + 3670016;             // 262144
    float* e2   = ws + 3932160;             // 1024
    int*   idxi = (int*)(ws + 3933184);     // 4096
    const long FLOAT_WORDS = 3937280;
    float* uin  = giB;
    float* mlph = giB + 524288;
    float* t1   = giA;

    u16* wsu = (u16*)((char*)d_ws + FLOAT_WORDS * sizeof(float));

    // ---- fast layout (u16 offsets) ----
    u16* wihF_h = wsu;             u16* wihF_l = wsu + 1572864;
    u16* whhP_h = wsu + 3145728;   u16* whhP_l = wsu + 6291456;
    u16* wqF_h  = wsu + 9437184;   u16* wqF_l  = wsu + 9961472;
    u16* uw1F_h = wsu + 10485760;  u16* uw1F_l = wsu + 12058624;
    u16* uw2F_h = wsu + 13631488;  u16* uw2F_l = wsu + 14680064;
    u16* pw1F_h = wsu + 15728640;  u16* pw1F_l = wsu + 16252928;
    u16* pw2F_h = wsu + 16777216;  u16* pw2F_l = wsu + 17301504;
    u16* hh_hi[2] = { wsu + 17825792, wsu + 18874368 };
    u16* hh_lo[2] = { wsu + 18350080, wsu + 19398656 };
    u16* xp_h[2]  = { wsu + 19922944, wsu + 20447232 };
    u16* xp_l[2]  = { wsu + 20185088, wsu + 20709376 };
    const size_t NEED_FAST = FLOAT_WORDS * sizeof(float) + (size_t)20971520 * 2;

    // ---- legacy layout ----
    u16* whh_h = wsu;            u16* whh_l = wsu + 3145728;
    u16* wih_h = wsu + 6291456;  u16* wih_l = wsu + 7864320;
    u16* wq_h  = wsu + 9437184;  u16* wq_l  = wsu + 9961472;
    u16* uw1_h = wsu + 10485760; u16* uw1_l = wsu + 11534336;
    u16* uw2_h = wsu + 12582912; u16* uw2_l = wsu + 13631488;
    u16* pw1_h = wsu + 14680064; u16* pw1_l = wsu + 15204352;
    u16* pw2_h = wsu + 15728640; u16* pw2_l = wsu + 16252928;
    const size_t NEED_BPRE = FLOAT_WORDS * sizeof(float) + (size_t)16777216 * 2;

    const bool fast = ws_size >= NEED_FAST;
    const bool bpre = ws_size >= NEED_BPRE;

    float* out = (float*)d_out;
    const long o_idx   = 0;
    const long o_quant = o_idx   + (long)B_ * K_;
    const long o_narr  = o_quant + (long)B_ * K_ * C_;
    const long o_unc   = o_narr  + (long)B_ * BN_;
    const long o_pred  = o_unc   + (long)B_ * H_;
    const long o_loss  = o_pred  + (long)B_ * BN_;
    const long o_lh    = o_loss  + 1;

    float* hB = out + o_unc;
    float* hbuf[2] = { hA, hB };
    float* gibuf[2] = { giA, giB };

    hipMemsetAsync(hA, 0, (size_t)B_ * H_ * sizeof(float), stream);
    emb_norm<<<4, 256, 0, stream>>>(emb, e2, out + o_loss);

    auto mkargs = [&](const float* A, long lda, const float* Bw, const u16* Bh, const u16* Bl,
                      const float* bias, float* C, long ldc, int K) {
        GArgs g; g.A = A; g.lda = lda; g.Bw = Bw; g.Bhi = Bh; g.Blo = Bl;
        g.bias = bias; g.C = C; g.ldc = ldc; g.K = K; return g;
    };
    auto cvt = [&](const float* s, u16* hi, u16* lo, long n) {
        long n8 = n / 8;
        to_hilo<<<(int)((n8 + 255) / 256), 256, 0, stream>>>(s, hi, lo, n8);
    };

    if (fast) {
        hipMemsetAsync(hh_hi[0], 0, (size_t)B_ * H_ * sizeof(u16), stream);
        hipMemsetAsync(hh_lo[0], 0, (size_t)B_ * H_ * sizeof(u16), stream);
        cvt(W_ih, wihF_h, wihF_l, (long)G3 * D_);
        to_hilo_perm<<<3072, 256, 0, stream>>>(W_hh, whhP_h, whhP_l);
        cvt(Wq,  wqF_h,  wqF_l,  (long)BN_ * H_);
        cvt(uW1, uw1F_h, uw1F_l, (long)H_ * (D_ + BN_));
        cvt(uW2, uw2F_h, uw2F_l, (long)H_ * H_);
        cvt(pW1, pw1F_h, pw1F_l, (long)H_ * BN_);
        cvt(pW2, pw2F_h, pw2F_l, (long)BN_ * H_);
        pack_x<<<16, 256, 0, stream>>>(x + (long)1 * D_, xp_h[1], xp_l[1]);

        // gi(0)
        GArgs g0 = mkargs(x, (long)W_ * D_, W_ih, wihF_h, wihF_l, b_ih, gibuf[0], G3, D_);
        hilo_gemm64<0, 1><<<dim3(48, 8), 256, 0, stream>>>(g0);

        for (int w = 0; w < W_; ++w) {
            FStep f;
            f.hAh = hh_hi[w & 1]; f.hAl = hh_lo[w & 1];
            f.h_in = hbuf[w & 1]; f.h_out = hbuf[(w + 1) & 1];
            f.hOh = hh_hi[(w + 1) & 1]; f.hOl = hh_lo[(w + 1) & 1];
            f.WPh = whhP_h; f.WPl = whhP_l;
            f.b_hh = b_hh;
            f.gi_in = gibuf[w & 1];
            f.xh = xp_h[(w + 1) & 1]; f.xl = xp_l[(w + 1) & 1];
            f.Wih = wihF_h; f.Wil = wihF_l;
            f.b_ih = b_ih;
            f.gi_out = gibuf[(w + 1) & 1];
            f.xpack_src = (w + 2 < W_) ? (x + (long)(w + 2) * D_) : nullptr;
            f.xph = xp_h[w & 1]; f.xpl = xp_l[w & 1];
            f.do_gi = (w + 1 < W_);
            gru_fused<<<528, 256, 0, stream>>>(f);
        }
        float* hfin = hbuf[0];

        auto gemm = [&](int act, GArgs g, int N, int M) {
            dim3 grid(N / 64, M / 64);
            if (act == 1) hilo_gemm64<1, 1><<<grid, 256, 0, stream>>>(g);
            else          hilo_gemm64<0, 1><<<grid, 256, 0, stream>>>(g);
        };
        gemm(0, mkargs(hfin, H_, Wq, wqF_h, wqF_l, bq, q, BN_, H_), BN_, B_);
        vq_fused<<<B_ * K_ / 32, 256, 0, stream>>>(q, emb, e2, out + o_idx, idxi);
        gather_loss<<<(B_ * K_ * C_) / 256, 256, 0, stream>>>(
            q, emb, idxi, out + o_quant, out + o_narr, out + o_loss);
        build_uin<<<(B_ * (D_ + BN_)) / 256, 256, 0, stream>>>(x, out + o_narr, uin);
        gemm(1, mkargs(uin, D_ + BN_, uW1, uw1F_h, uw1F_l, ub1, mlph, H_, D_ + BN_), H_, B_);
        gemm(0, mkargs(mlph, H_, uW2, uw2F_h, uw2F_l, ub2, out + o_unc, H_, H_), H_, B_);
        gemm(1, mkargs(out + o_narr, BN_, pW1, pw1F_h, pw1F_l, pb1, t1, H_, BN_), H_, B_);
        gemm(0, mkargs(t1, H_, pW2, pw2F_h, pw2F_l, pb2, out + o_pred, BN_, H_), BN_, B_);
        copy_f<<<(B_ * H_) / 256, 256, 0, stream>>>(hfin, out + o_lh);
        return;
    }

    // =============== legacy path (round-4) ===============
    if (bpre) {
        cvt(W_hh, whh_h, whh_l, (long)G3 * H_);
        cvt(W_ih, wih_h, wih_l, (long)G3 * D_);
        cvt(Wq,   wq_h,  wq_l,  (long)BN_ * H_);
        cvt(uW1,  uw1_h, uw1_l, (long)H_ * (D_ + BN_));
        cvt(uW2,  uw2_h, uw2_l, (long)H_ * H_);
        cvt(pW1,  pw1_h, pw1_l, (long)H_ * BN_);
        cvt(pW2,  pw2_h, pw2_l, (long)BN_ * H_);
    }

    {
        GArgs g0 = mkargs(x, (long)W_ * D_, W_ih, wih_h, wih_l, b_ih, gibuf[0], G3, D_);
        if (bpre) hilo_gemm64<0, 1><<<dim3(48, 8), 256, 0, stream>>>(g0);
        else      hilo_gemm64<0, 0><<<dim3(48, 8), 256, 0, stream>>>(g0);
    }

    for (int w = 0; w < W_; ++w) {
        StepArgs s;
        s.h_in  = hbuf[w & 1];
        s.h_out = hbuf[(w + 1) & 1];
        s.W_hh = W_hh; s.Whh_h = whh_h; s.Whh_l = whh_l;
        s.gi = gibuf[w & 1];
        s.b_hh = b_hh;
        s.xw = (w + 1 < W_) ? (x + (long)(w + 1) * D_) : nullptr;
        s.W_ih = W_ih; s.Wih_h = wih_h; s.Wih_l = wih_l;
        s.b_ih = b_ih;
        s.gi_out = gibuf[(w + 1) & 1];
        if (bpre) gru_step2<1><<<640, 256, 0, stream>>>(s);
        else      gru_step2<0><<<640, 256, 0, stream>>>(s);
    }
    float* hfin = hbuf[0];

    auto gemmL = [&](int act, GArgs g, int N, int M) {
        dim3 grid(N / 64, M / 64);
        if (bpre) {
            if (act == 1) hilo_gemm64<1, 1><<<grid, 256, 0, stream>>>(g);
            else          hilo_gemm64<0, 1><<<grid, 256, 0, stream>>>(g);
        } else {
            if (act == 1) hilo_gemm64<1, 0><<<grid, 256, 0, stream>>>(g);
            else          hilo_gemm64<0, 0><<<grid, 256, 0, stream>>>(g);
        }
    };

    gemmL(0, mkargs(hfin, H_, Wq, wq_h, wq_l, bq, q, BN_, H_), BN_, B_);
    vq_fused<<<B_ * K_ / 32, 256, 0, stream>>>(q, emb, e2, out + o_idx, idxi);
    gather_loss<<<(B_ * K_ * C_) / 256, 256, 0, stream>>>(
        q, emb, idxi, out + o_quant, out + o_narr, out + o_loss);
    build_uin<<<(B_ * (D_ + BN_)) / 256, 256, 0, stream>>>(x, out + o_narr, uin);
    gemmL(1, mkargs(uin, D_ + BN_, uW1, uw1_h, uw1_l, ub1, mlph, H_, D_ + BN_), H_, B_);
    gemmL(0, mkargs(mlph, H_, uW2, uw2_h, uw2_l, ub2, out + o_unc, H_, H_), H_, B_);
    gemmL(1, mkargs(out + o_narr, BN_, pW1, pw1_h, pw1_l, pb1, t1, H_, BN_), H_, B_);
    gemmL(0, mkargs(t1, H_, pW2, pw2_h, pw2_l, pb2, out + o_pred, BN_, H_), BN_, B_);
    copy_f<<<(B_ * H_) / 256, 256, 0, stream>>>(hfin, out + o_lh);
}

// Round 6
// 1904.836 us; speedup vs baseline: 3.0545x; 1.0942x over previous
//
#include <hip/hip_runtime.h>
#include <math.h>

#define B_ 512
#define W_ 64
#define D_ 512
#define H_ 1024
#define NC_ 1024
#define K_ 8
#define C_ 64
#define BN_ 512
#define G3 (3*H_)

typedef unsigned short u16;
typedef __attribute__((ext_vector_type(8))) short bf16x8;
typedef __attribute__((ext_vector_type(4))) float f32x4;

__device__ __forceinline__ float bf_up(u16 h) { return __uint_as_float(((unsigned)h) << 16); }
__device__ __forceinline__ u16 bf_rn(float x) {
    unsigned u = __float_as_uint(x);
    return (u16)((u + 0x7FFFu + ((u >> 16) & 1u)) >> 16);
}

__device__ __forceinline__ void split8v(float4 x, float4 y, uint4& H, uint4& L) {
    float v[8] = {x.x, x.y, x.z, x.w, y.x, y.y, y.z, y.w};
    union { u16 s[8]; uint4 u; } Hh, Ll;
    #pragma unroll
    for (int i = 0; i < 8; ++i) {
        unsigned ub = __float_as_uint(v[i]);
        u16 hi = (u16)(ub >> 16);
        Hh.s[i] = hi;
        Ll.s[i] = bf_rn(v[i] - bf_up(hi));
    }
    H = Hh.u; L = Ll.u;
}

__device__ __forceinline__ void cvt_store8(u16* ph, u16* pl, float4 x, float4 y) {
    uint4 H, L; split8v(x, y, H, L);
    *(uint4*)ph = H;
    *(uint4*)pl = L;
}

struct GArgs {
    const float* A;  long lda;
    const float* Bw;
    const u16* Bhi;  const u16* Blo;
    const float* bias;
    float* C;  long ldc;
    int K;
};

// ---- generic hi/lo GEMM (tail GEMMs + fallback), M64xN64, BK=32 ----
template<int ACT, int BPRE>
__device__ __forceinline__ void gemm_core64(const GArgs g, int bx, int by, u16* lds)
{
    u16* Ah = lds;
    u16* Al = lds + 2560;
    u16* Bh = lds + 5120;
    u16* Bl = lds + 7680;
    const int tid = threadIdx.x;
    const int l = tid & 63, wv = tid >> 6;
    const int m0 = by * 64, n0 = bx * 64;
    const int sr = tid >> 2, sc = (tid & 3) * 8;
    const int sA = sr * 40 + sc;

    const float* Ap = g.A + (long)(m0 + sr) * g.lda + sc;
    const float* Bp = 0; const u16 *Bph = 0, *Bpl = 0;
    if (BPRE) { Bph = g.Bhi + (long)(n0 + sr) * g.K + sc; Bpl = g.Blo + (long)(n0 + sr) * g.K + sc; }
    else      { Bp  = g.Bw  + (long)(n0 + sr) * g.K + sc; }

    f32x4 acc[4] = {};

    for (int k0 = 0; k0 < g.K; k0 += 32) {
        float4 a0 = *(const float4*)(Ap + k0);
        float4 a1 = *(const float4*)(Ap + k0 + 4);
        float4 b0, b1; uint4 h0, l0;
        if (BPRE) { h0 = *(const uint4*)(Bph + k0); l0 = *(const uint4*)(Bpl + k0); }
        else      { b0 = *(const float4*)(Bp + k0); b1 = *(const float4*)(Bp + k0 + 4); }
        __syncthreads();
        cvt_store8(Ah + sA, Al + sA, a0, a1);
        if (BPRE) { *(uint4*)(Bh + sA) = h0; *(uint4*)(Bl + sA) = l0; }
        else      { cvt_store8(Bh + sA, Bl + sA, b0, b1); }
        __syncthreads();

        const int fr = (l & 15) * 40 + (l >> 4) * 8;
        bf16x8 bh = *(const bf16x8*)(Bh + wv * 640 + fr);
        bf16x8 bl = *(const bf16x8*)(Bl + wv * 640 + fr);
        #pragma unroll
        for (int mt = 0; mt < 4; ++mt) {
            bf16x8 ah = *(const bf16x8*)(Ah + mt * 640 + fr);
            bf16x8 al = *(const bf16x8*)(Al + mt * 640 + fr);
            acc[mt] = __builtin_amdgcn_mfma_f32_16x16x32_bf16(ah, bh, acc[mt], 0, 0, 0);
            acc[mt] = __builtin_amdgcn_mfma_f32_16x16x32_bf16(ah, bl, acc[mt], 0, 0, 0);
            acc[mt] = __builtin_amdgcn_mfma_f32_16x16x32_bf16(al, bh, acc[mt], 0, 0, 0);
        }
    }

    const int n = n0 + wv * 16 + (l & 15);
    const float bv = g.bias[n];
    #pragma unroll
    for (int mt = 0; mt < 4; ++mt) {
        #pragma unroll
        for (int r = 0; r < 4; ++r) {
            int m = m0 + mt * 16 + (l >> 4) * 4 + r;
            float v = acc[mt][r] + bv;
            if (ACT == 1) v = v / (1.f + expf(-v));
            g.C[(long)m * g.ldc + n] = v;
        }
    }
}

template<int ACT, int BPRE>
__global__ __launch_bounds__(256)
void hilo_gemm64(GArgs g) {
    __shared__ u16 lds[10240];
    gemm_core64<ACT, BPRE>(g, blockIdx.x, blockIdx.y, lds);
}

// =================== round-6 fused GRU step: B frag-direct from global ===================
struct FS2 {
    const u16* hAh; const u16* hAl;    // split h(w)  [512][1024]
    const float* h_in; float* h_out;   // fp32 h ping-pong
    u16* hOh; u16* hOl;                // split h(w+1)
    const u16* WFh; const u16* WFl;    // whh frag-ordered (48-perm), NKC=32
    const float* b_hh;
    const float* gi_in;                // gi(w) [512][3072] (b_ih included)
    const u16* xh; const u16* xl;      // split x slice (w+1) [512][512]
    const u16* XFh; const u16* XFl;    // wih frag-ordered (plain), NKC=16
    const float* b_ih;
    float* gi_out;                     // gi(w+1)
    const float* xpack_src;            // x + (w+2)*D or null
    u16* xph; u16* xpl;
    int do_gi;
};

// tile 64m x 96n; waves: mh = wv&1 (32m), nh = wv>>1 (48n = one gate triple)
// A staged in LDS (hi/lo, dbuf 20KB); B loaded frag-direct global->reg.
template<int NKC, int EPI>   // EPI 0: GH + GRU epilogue; 1: GI plain store
__device__ __forceinline__ void step_core(const FS2& f, int bx, int by, u16* lds)
{
    const int tid = threadIdx.x, l = tid & 63, wv = tid >> 6;
    const int mh = wv & 1, nh = wv >> 1;
    const int m0 = by * 64;
    const int lda = NKC * 32;

    const u16 *Ah_g, *Al_g, *BFh, *BFl;
    if (EPI == 0) { Ah_g = f.hAh; Al_g = f.hAl; BFh = f.WFh; BFl = f.WFl; }
    else          { Ah_g = f.xh;  Al_g = f.xl;  BFh = f.XFh; BFl = f.XFl; }

    const int row = tid >> 2, c8 = (tid & 3) * 8;
    const u16* pAh = Ah_g + (long)(m0 + row) * lda + c8;
    const u16* pAl = Al_g + (long)(m0 + row) * lda + c8;
    const int sOff = row * 40 + c8;

    const int nfb = bx * 6 + nh * 3;
    const u16* pBh[3]; const u16* pBl[3];
    #pragma unroll
    for (int g = 0; g < 3; ++g) {
        long o = (((long)(nfb + g) * NKC) * 64 + l) * 8;
        pBh[g] = BFh + o; pBl[g] = BFl + o;
    }

    uint4 sa, sl;
    uint4 bhC[3], blC[3], bhN[3], blN[3];

    #define LDA_(kc) { sa = *(const uint4*)(pAh + (kc)*32); sl = *(const uint4*)(pAl + (kc)*32); }
    #define WRA_(bi) { u16* bb = lds + (bi)*5120; *(uint4*)(bb + sOff) = sa; *(uint4*)(bb + 2560 + sOff) = sl; }
    #define LDB_(kc, BH, BL) { long ko = (long)(kc)*512; \
        BH[0] = *(const uint4*)(pBh[0]+ko); BH[1] = *(const uint4*)(pBh[1]+ko); BH[2] = *(const uint4*)(pBh[2]+ko); \
        BL[0] = *(const uint4*)(pBl[0]+ko); BL[1] = *(const uint4*)(pBl[1]+ko); BL[2] = *(const uint4*)(pBl[2]+ko); }

    f32x4 acc[2][3] = {};
    const int frA = (mh * 32 + (l & 15)) * 40 + (l >> 4) * 8;

    LDA_(0); WRA_(0); LDB_(0, bhC, blC);
    for (int kc = 0; kc < NKC; ++kc) {
        const bool more = (kc + 1 < NKC);
        if (more) { LDA_(kc + 1); LDB_(kc + 1, bhN, blN); }
        __syncthreads();
        u16* buf = lds + (kc & 1) * 5120;
        bf16x8 a_h[2], a_l[2];
        #pragma unroll
        for (int mt = 0; mt < 2; ++mt) {
            a_h[mt] = *(const bf16x8*)(buf + frA + mt * 640);
            a_l[mt] = *(const bf16x8*)(buf + 2560 + frA + mt * 640);
        }
        #pragma unroll
        for (int g = 0; g < 3; ++g) {
            bf16x8 bh = *(const bf16x8*)&bhC[g];
            bf16x8 bl = *(const bf16x8*)&blC[g];
            #pragma unroll
            for (int mt = 0; mt < 2; ++mt) {
                acc[mt][g] = __builtin_amdgcn_mfma_f32_16x16x32_bf16(a_h[mt], bh, acc[mt][g], 0, 0, 0);
                acc[mt][g] = __builtin_amdgcn_mfma_f32_16x16x32_bf16(a_h[mt], bl, acc[mt][g], 0, 0, 0);
                acc[mt][g] = __builtin_amdgcn_mfma_f32_16x16x32_bf16(a_l[mt], bh, acc[mt][g], 0, 0, 0);
            }
        }
        if (more) {
            WRA_((kc + 1) & 1);
            #pragma unroll
            for (int g = 0; g < 3; ++g) { bhC[g] = bhN[g]; blC[g] = blN[g]; }
        }
    }
    #undef LDA_
    #undef WRA_
    #undef LDB_

    if (EPI == 0) {
        const int j = (bx * 2 + nh) * 16 + (l & 15);
        const float bhr = f.b_hh[j], bhz = f.b_hh[H_ + j], bhn = f.b_hh[2 * H_ + j];
        #pragma unroll
        for (int mt = 0; mt < 2; ++mt) {
            #pragma unroll
            for (int r = 0; r < 4; ++r) {
                int m = m0 + mh * 32 + mt * 16 + (l >> 4) * 4 + r;
                const float* gib = f.gi_in + (long)m * G3;
                float ir = gib[j], iz = gib[H_ + j], inn = gib[2 * H_ + j];
                float hr = acc[mt][0][r] + bhr;
                float hz = acc[mt][1][r] + bhz;
                float hn = acc[mt][2][r] + bhn;
                float rg = 1.f / (1.f + expf(-(ir + hr)));
                float zg = 1.f / (1.f + expf(-(iz + hz)));
                float ng = tanhf(inn + rg * hn);
                float hv = (1.f - zg) * ng + zg * f.h_in[(long)m * H_ + j];
                long oidx = (long)m * H_ + j;
                f.h_out[oidx] = hv;
                unsigned ub = __float_as_uint(hv);
                u16 hh = (u16)(ub >> 16);
                f.hOh[oidx] = hh;
                f.hOl[oidx] = bf_rn(hv - bf_up(hh));
            }
        }
    } else {
        #pragma unroll
        for (int g = 0; g < 3; ++g) {
            const int n = (nfb + g) * 16 + (l & 15);
            const float bv = f.b_ih[n];
            #pragma unroll
            for (int mt = 0; mt < 2; ++mt) {
                #pragma unroll
                for (int r = 0; r < 4; ++r) {
                    int m = m0 + mh * 32 + mt * 16 + (l >> 4) * 4 + r;
                    f.gi_out[(long)m * G3 + n] = acc[mt][g][r] + bv;
                }
            }
        }
    }
}

__device__ __forceinline__ void pack_slice_dev(const float* src, u16* dh, u16* dl,
                                               int blk, int tid)
{
    #pragma unroll
    for (int it = 0; it < 16; ++it) {
        int e4 = blk * 4096 + it * 256 + tid;   // float4 index, 65536 total
        int b = e4 >> 7, dd = (e4 & 127) * 4;
        float4 v = *(const float4*)(src + (long)b * (W_ * D_) + dd);
        union { u16 s[4]; uint2 u; } Hh, Ll;
        float vv[4] = {v.x, v.y, v.z, v.w};
        #pragma unroll
        for (int i = 0; i < 4; ++i) {
            unsigned ub = __float_as_uint(vv[i]);
            u16 hi = (u16)(ub >> 16);
            Hh.s[i] = hi;
            Ll.s[i] = bf_rn(vv[i] - bf_up(hi));
        }
        long o = (long)b * D_ + dd;
        *(uint2*)(dh + o) = Hh.u;
        *(uint2*)(dl + o) = Ll.u;
    }
}

__global__ __launch_bounds__(256)
void gru_fused2(FS2 f)
{
    __shared__ u16 lds[10240];
    const int id = blockIdx.x;
    if (id < 256) {
        step_core<32, 0>(f, id & 31, id >> 5, lds);
    } else if (id < 512) {
        if (!f.do_gi) return;
        int id2 = id - 256;
        step_core<16, 1>(f, id2 & 31, id2 >> 5, lds);
    } else {
        if (!f.xpack_src) return;
        pack_slice_dev(f.xpack_src, f.xph, f.xpl, id - 512, threadIdx.x);
    }
}

__global__ __launch_bounds__(256)
void gi_init(FS2 f)
{
    __shared__ u16 lds[10240];
    step_core<16, 1>(f, blockIdx.x & 31, blockIdx.x >> 5, lds);
}

__global__ __launch_bounds__(256)
void pack_x(const float* src, u16* dh, u16* dl)
{
    pack_slice_dev(src, dh, dl, blockIdx.x, threadIdx.x);
}

// ---------------- prep: fp32 -> hi/lo row-major split (tail weights) ----------------
__global__ __launch_bounds__(256)
void to_hilo(const float* __restrict__ src, u16* __restrict__ hi, u16* __restrict__ lo, long n8) {
    long i = (long)blockIdx.x * 256 + threadIdx.x;
    if (i >= n8) return;
    float4 a = ((const float4*)src)[2 * i];
    float4 b = ((const float4*)src)[2 * i + 1];
    uint4 H, L; split8v(a, b, H, L);
    ((uint4*)hi)[i] = H;
    ((uint4*)lo)[i] = L;
}

// whh -> frag order with 48-perm: frag col p = nf*16+(l&15); src row = g*H + jg*16 + jl
__global__ __launch_bounds__(256)
void prep_whh(const float* __restrict__ W, u16* __restrict__ fh, u16* __restrict__ fl)
{
    long t = (long)blockIdx.x * 256 + threadIdx.x;   // 192*32*64
    if (t >= (long)192 * 32 * 64) return;
    int l = (int)(t & 63);
    long nk = t >> 6;
    int kc = (int)(nk & 31);
    int nf = (int)(nk >> 5);
    int p = nf * 16 + (l & 15);
    int jg = p / 48, g = (p % 48) >> 4, jl = p & 15;
    int srow = g * H_ + jg * 16 + jl;
    int k0 = kc * 32 + (l >> 4) * 8;
    float4 v0 = *(const float4*)(W + (long)srow * H_ + k0);
    float4 v1 = *(const float4*)(W + (long)srow * H_ + k0 + 4);
    uint4 H, L; split8v(v0, v1, H, L);
    ((uint4*)fh)[t] = H;
    ((uint4*)fl)[t] = L;
}

// wih -> frag order plain: src row = nf*16+(l&15), K=512
__global__ __launch_bounds__(256)
void prep_wih(const float* __restrict__ W, u16* __restrict__ fh, u16* __restrict__ fl)
{
    long t = (long)blockIdx.x * 256 + threadIdx.x;   // 192*16*64
    if (t >= (long)192 * 16 * 64) return;
    int l = (int)(t & 63);
    long nk = t >> 6;
    int kc = (int)(nk & 15);
    int nf = (int)(nk >> 4);
    int srow = nf * 16 + (l & 15);
    int k0 = kc * 32 + (l >> 4) * 8;
    float4 v0 = *(const float4*)(W + (long)srow * D_ + k0);
    float4 v1 = *(const float4*)(W + (long)srow * D_ + k0 + 4);
    uint4 H, L; split8v(v0, v1, H, L);
    ((uint4*)fh)[t] = H;
    ((uint4*)fl)[t] = L;
}

// =================== legacy fallback (round-4, fp32-direct) ===================
struct StepArgs {
    const float* h_in;  float* h_out;
    const float* W_hh;
    const float* gi;
    const float* b_hh;
    const float* xw;
    const float* W_ih;
    const float* b_ih;
    float* gi_out;
};

__global__ __launch_bounds__(256)
void gru_step2(StepArgs s)
{
    __shared__ u16 lds[17920];
    const int id = blockIdx.x;
    const int tid = threadIdx.x;
    if (id >= 256) {
        if (!s.xw) return;
        int id2 = id - 256;
        GArgs g;
        g.A = s.xw; g.lda = (long)W_ * D_;
        g.Bw = s.W_ih; g.Bhi = 0; g.Blo = 0;
        g.bias = s.b_ih; g.C = s.gi_out; g.ldc = G3; g.K = D_;
        gemm_core64<0, 0>(g, id2 % 48, id2 / 48, lds);
        return;
    }
    u16* Ah = lds;
    u16* Al = lds + 1280;
    u16* Bh = lds + 2560;
    u16* Bl = lds + 10240;
    const int by = id >> 4, bx = id & 15;
    const int l = tid & 63, wv = tid >> 6;
    const int m0 = by * 32, j0 = bx * 64;
    const int sr = tid >> 2, sc = (tid & 3) * 8;
    const int sA = sr * 40 + sc;

    const float* Ap = s.h_in + (long)(m0 + (tid >> 2)) * H_ + sc;

    f32x4 acc[2][3] = {};

    for (int k0 = 0; k0 < H_; k0 += 32) {
        float4 a0, a1;
        if (tid < 128) {
            a0 = *(const float4*)(Ap + k0);
            a1 = *(const float4*)(Ap + k0 + 4);
        }
        float4 bf0[3], bf1[3];
        #pragma unroll
        for (int g = 0; g < 3; ++g) {
            long rowp = (long)(g * H_ + j0 + sr);
            bf0[g] = *(const float4*)(s.W_hh + rowp * H_ + k0 + sc);
            bf1[g] = *(const float4*)(s.W_hh + rowp * H_ + k0 + sc + 4);
        }
        __syncthreads();
        if (tid < 128) cvt_store8(Ah + sA, Al + sA, a0, a1);
        #pragma unroll
        for (int g = 0; g < 3; ++g)
            cvt_store8(Bh + g * 2560 + sA, Bl + g * 2560 + sA, bf0[g], bf1[g]);
        __syncthreads();

        const int fr = (l & 15) * 40 + (l >> 4) * 8;
        bf16x8 bhf[3], blf[3];
        #pragma unroll
        for (int g = 0; g < 3; ++g) {
            bhf[g] = *(const bf16x8*)(Bh + g * 2560 + wv * 640 + fr);
            blf[g] = *(const bf16x8*)(Bl + g * 2560 + wv * 640 + fr);
        }
        #pragma unroll
        for (int mt = 0; mt < 2; ++mt) {
            bf16x8 ah = *(const bf16x8*)(Ah + mt * 640 + fr);
            bf16x8 al = *(const bf16x8*)(Al + mt * 640 + fr);
            #pragma unroll
            for (int g = 0; g < 3; ++g) {
                acc[mt][g] = __builtin_amdgcn_mfma_f32_16x16x32_bf16(ah, bhf[g], acc[mt][g], 0, 0, 0);
                acc[mt][g] = __builtin_amdgcn_mfma_f32_16x16x32_bf16(ah, blf[g], acc[mt][g], 0, 0, 0);
                acc[mt][g] = __builtin_amdgcn_mfma_f32_16x16x32_bf16(al, bhf[g], acc[mt][g], 0, 0, 0);
            }
        }
    }

    const int j = j0 + wv * 16 + (l & 15);
    const float bhr = s.b_hh[j], bhz = s.b_hh[H_ + j], bhn = s.b_hh[2 * H_ + j];
    #pragma unroll
    for (int mt = 0; mt < 2; ++mt) {
        #pragma unroll
        for (int r = 0; r < 4; ++r) {
            int m = m0 + mt * 16 + (l >> 4) * 4 + r;
            const float* gib = s.gi + (long)m * G3;
            float ir = gib[j], iz = gib[H_ + j], inn = gib[2 * H_ + j];
            float hr = acc[mt][0][r] + bhr;
            float hz = acc[mt][1][r] + bhz;
            float hn = acc[mt][2][r] + bhn;
            float rg = 1.f / (1.f + expf(-(ir + hr)));
            float zg = 1.f / (1.f + expf(-(iz + hz)));
            float ng = tanhf(inn + rg * hn);
            s.h_out[(long)m * H_ + j] = (1.f - zg) * ng + zg * s.h_in[(long)m * H_ + j];
        }
    }
}

// ---------------- misc small kernels ----------------
__global__ void emb_norm(const float* __restrict__ emb, float* __restrict__ e2,
                         float* __restrict__ loss_slot)
{
    int n = blockIdx.x * 256 + threadIdx.x;
    if (n == 0) *loss_slot = 0.f;
    if (n < NC_) {
        const float4* e4 = (const float4*)(emb + (long)n * C_);
        float s = 0.f;
        #pragma unroll
        for (int c = 0; c < 16; ++c) { float4 e = e4[c]; s += e.x*e.x + e.y*e.y + e.z*e.z + e.w*e.w; }
        e2[n] = s;
    }
}

// ---- VQ: 256 blocks x 16 queries; q row in regs, emb chunk staged [code][68] ----
__global__ __launch_bounds__(256)
void vq16(const float* __restrict__ q, const float* __restrict__ emb,
          const float* __restrict__ e2, float* __restrict__ out_f,
          int* __restrict__ out_i)
{
    __shared__ float es[128 * 68];
    const int blk = blockIdx.x, tid = threadIdx.x;
    const int qg = tid >> 4, sI = tid & 15;
    float4 qr[16];
    {
        const float4* qrow = (const float4*)(q + (long)(blk * 16 + qg) * C_);
        #pragma unroll
        for (int i = 0; i < 16; ++i) qr[i] = qrow[i];
    }
    float bestv = 3.4e38f; int besti = 0;

    for (int n0 = 0; n0 < NC_; n0 += 128) {
        __syncthreads();
        const float4* e4 = (const float4*)(emb + (long)n0 * C_);
        #pragma unroll
        for (int i = tid; i < 2048; i += 256) {
            int code = i >> 4, c4 = i & 15;
            *(float4*)(es + code * 68 + c4 * 4) = e4[i];
        }
        __syncthreads();
        #pragma unroll
        for (int jj = 0; jj < 8; ++jj) {
            int code = sI + 16 * jj;
            const float* er = es + code * 68;
            float dot = 0.f;
            #pragma unroll
            for (int c4 = 0; c4 < 16; ++c4) {
                float4 ev = *(const float4*)(er + c4 * 4);
                dot += ev.x * qr[c4].x + ev.y * qr[c4].y + ev.z * qr[c4].z + ev.w * qr[c4].w;
            }
            float d = e2[n0 + code] - 2.f * dot;
            if (d < bestv) { bestv = d; besti = n0 + code; }
        }
    }
    #pragma unroll
    for (int m = 1; m <= 8; m <<= 1) {
        float ov = __shfl_xor(bestv, m);
        int   oi = __shfl_xor(besti, m);
        if (ov < bestv || (ov == bestv && oi < besti)) { bestv = ov; besti = oi; }
    }
    if (sI == 0) {
        int bk = blk * 16 + qg;
        out_f[bk] = (float)besti;
        out_i[bk] = besti;
    }
}

__global__ __launch_bounds__(256)
void gather_loss(const float* __restrict__ q, const float* __restrict__ emb,
                 const int* __restrict__ idx, float* __restrict__ quant_out,
                 float* __restrict__ narr_out, float* __restrict__ loss_slot)
{
    int i = blockIdx.x * 256 + threadIdx.x;
    int bk = i >> 6;
    int c  = i & 63;
    float e  = emb[(long)idx[bk] * C_ + c];
    float qv = q[i];
    quant_out[i] = e;
    narr_out[i]  = e;
    float dsq = (qv - e) * (qv - e);
    __shared__ float red[256];
    red[threadIdx.x] = dsq;
    __syncthreads();
    for (int s = 128; s > 0; s >>= 1) {
        if (threadIdx.x < s) red[threadIdx.x] += red[threadIdx.x + s];
        __syncthreads();
    }
    if (threadIdx.x == 0)
        atomicAdd(loss_slot, red[0] * (1.25f / (float)(B_ * K_ * C_)));
}

__global__ __launch_bounds__(256)
void build_uin(const float* __restrict__ x, const float* __restrict__ narr,
               float* __restrict__ uin)
{
    int i = blockIdx.x * 256 + threadIdx.x;
    int b = i >> 10;
    int j = i & 1023;
    uin[i] = (j < D_) ? x[(long)b * W_ * D_ + (long)(W_ - 1) * D_ + j]
                      : narr[(long)b * BN_ + (j - D_)];
}

__global__ __launch_bounds__(256)
void copy_f(const float* __restrict__ src, float* __restrict__ dst)
{
    int i = blockIdx.x * 256 + threadIdx.x;
    dst[i] = src[i];
}

extern "C" void kernel_launch(void* const* d_in, const int* in_sizes, int n_in,
                              void* d_out, int out_size, void* d_ws, size_t ws_size,
                              hipStream_t stream)
{
    (void)in_sizes; (void)n_in; (void)out_size;
    const float* x     = (const float*)d_in[0];
    const float* W_ih  = (const float*)d_in[1];
    const float* W_hh  = (const float*)d_in[2];
    const float* b_ih  = (const float*)d_in[3];
    const float* b_hh  = (const float*)d_in[4];
    const float* Wq    = (const float*)d_in[5];
    const float* bq    = (const float*)d_in[6];
    const float* emb   = (const float*)d_in[7];
    const float* uW1   = (const float*)d_in[8];
    const float* ub1   = (const float*)d_in[9];
    const float* uW2   = (const float*)d_in[10];
    const float* ub2   = (const float*)d_in[11];
    const float* pW1   = (const float*)d_in[12];
    const float* pb1   = (const float*)d_in[13];
    const float* pW2   = (const float*)d_in[14];
    const float* pb2   = (const float*)d_in[15];

    float* ws = (float*)d_ws;
    float* hA   = ws;                       // 524288
    float* giA  = ws + 524288;              // 1572864
    float* giB  = ws + 2097152;             // 1572864
    float* q    = ws + 3670016;             // 262144
    float* e2   = ws + 3932160;             // 1024
    int*   idxi = (int*)(ws + 3933184);     // 4096
    const long FLOAT_WORDS = 3937280;
    float* uin  = giB;
    float* mlph = giB + 524288;
    float* t1   = giA;

    u16* wsu = (u16*)((char*)d_ws + FLOAT_WORDS * sizeof(float));
    // frag-ordered GRU weights
    u16* whhF_h = wsu;             u16* whhF_l = wsu + 3145728;
    u16* wihF_h = wsu + 6291456;   u16* wihF_l = wsu + 7864320;
    // row-major tail weights
    u16* wqR_h  = wsu + 9437184;   u16* wqR_l  = wsu + 9961472;
    u16* uw1R_h = wsu + 10485760;  u16* uw1R_l = wsu + 11534336;
    u16* uw2R_h = wsu + 12582912;  u16* uw2R_l = wsu + 13631488;
    u16* pw1R_h = wsu + 14680064;  u16* pw1R_l = wsu + 15204352;
    u16* pw2R_h = wsu + 15728640;  u16* pw2R_l = wsu + 16252928;
    // state splits
    u16* hh_hi[2] = { wsu + 16777216, wsu + 17301504 };
    u16* hh_lo[2] = { wsu + 17825792, wsu + 18350080 };
    u16* xp_h[2]  = { wsu + 18874368, wsu + 19136512 };
    u16* xp_l[2]  = { wsu + 19398656, wsu + 19660800 };
    const size_t NEED_NEW = FLOAT_WORDS * sizeof(float) + (size_t)19922944 * 2;
    const bool fast = ws_size >= NEED_NEW;

    float* out = (float*)d_out;
    const long o_idx   = 0;
    const long o_quant = o_idx   + (long)B_ * K_;
    const long o_narr  = o_quant + (long)B_ * K_ * C_;
    const long o_unc   = o_narr  + (long)B_ * BN_;
    const long o_pred  = o_unc   + (long)B_ * H_;
    const long o_loss  = o_pred  + (long)B_ * BN_;
    const long o_lh    = o_loss  + 1;

    float* hB = out + o_unc;
    float* hbuf[2] = { hA, hB };
    float* gibuf[2] = { giA, giB };

    hipMemsetAsync(hA, 0, (size_t)B_ * H_ * sizeof(float), stream);
    emb_norm<<<4, 256, 0, stream>>>(emb, e2, out + o_loss);

    auto mkargs = [&](const float* A, long lda, const float* Bw, const u16* Bh, const u16* Bl,
                      const float* bias, float* C, long ldc, int Kd) {
        GArgs g; g.A = A; g.lda = lda; g.Bw = Bw; g.Bhi = Bh; g.Blo = Bl;
        g.bias = bias; g.C = C; g.ldc = ldc; g.K = Kd; return g;
    };
    auto cvt = [&](const float* s, u16* hi, u16* lo, long n) {
        long n8 = n / 8;
        to_hilo<<<(int)((n8 + 255) / 256), 256, 0, stream>>>(s, hi, lo, n8);
    };

    if (fast) {
        hipMemsetAsync(hh_hi[0], 0, (size_t)B_ * H_ * sizeof(u16), stream);
        hipMemsetAsync(hh_lo[0], 0, (size_t)B_ * H_ * sizeof(u16), stream);
        prep_whh<<<1536, 256, 0, stream>>>(W_hh, whhF_h, whhF_l);
        prep_wih<<<768, 256, 0, stream>>>(W_ih, wihF_h, wihF_l);
        cvt(Wq,  wqR_h,  wqR_l,  (long)BN_ * H_);
        cvt(uW1, uw1R_h, uw1R_l, (long)H_ * (D_ + BN_));
        cvt(uW2, uw2R_h, uw2R_l, (long)H_ * H_);
        cvt(pW1, pw1R_h, pw1R_l, (long)H_ * BN_);
        cvt(pW2, pw2R_h, pw2R_l, (long)BN_ * H_);
        pack_x<<<16, 256, 0, stream>>>(x, xp_h[0], xp_l[0]);
        pack_x<<<16, 256, 0, stream>>>(x + (long)1 * D_, xp_h[1], xp_l[1]);

        // gi(0) via GI core
        {
            FS2 f = {};
            f.xh = xp_h[0]; f.xl = xp_l[0];
            f.XFh = wihF_h; f.XFl = wihF_l;
            f.b_ih = b_ih; f.gi_out = gibuf[0];
            gi_init<<<256, 256, 0, stream>>>(f);
        }

        for (int w = 0; w < W_; ++w) {
            FS2 f;
            f.hAh = hh_hi[w & 1]; f.hAl = hh_lo[w & 1];
            f.h_in = hbuf[w & 1]; f.h_out = hbuf[(w + 1) & 1];
            f.hOh = hh_hi[(w + 1) & 1]; f.hOl = hh_lo[(w + 1) & 1];
            f.WFh = whhF_h; f.WFl = whhF_l;
            f.b_hh = b_hh;
            f.gi_in = gibuf[w & 1];
            f.xh = xp_h[(w + 1) & 1]; f.xl = xp_l[(w + 1) & 1];
            f.XFh = wihF_h; f.XFl = wihF_l;
            f.b_ih = b_ih;
            f.gi_out = gibuf[(w + 1) & 1];
            f.xpack_src = (w + 2 < W_) ? (x + (long)(w + 2) * D_) : nullptr;
            f.xph = xp_h[w & 1]; f.xpl = xp_l[w & 1];
            f.do_gi = (w + 1 < W_);
            gru_fused2<<<528, 256, 0, stream>>>(f);
        }
        float* hfin = hbuf[0];

        auto gemm = [&](int act, GArgs g, int N, int M) {
            dim3 grid(N / 64, M / 64);
            if (act == 1) hilo_gemm64<1, 1><<<grid, 256, 0, stream>>>(g);
            else          hilo_gemm64<0, 1><<<grid, 256, 0, stream>>>(g);
        };
        gemm(0, mkargs(hfin, H_, Wq, wqR_h, wqR_l, bq, q, BN_, H_), BN_, B_);
        vq16<<<256, 256, 0, stream>>>(q, emb, e2, out + o_idx, idxi);
        gather_loss<<<(B_ * K_ * C_) / 256, 256, 0, stream>>>(
            q, emb, idxi, out + o_quant, out + o_narr, out + o_loss);
        build_uin<<<(B_ * (D_ + BN_)) / 256, 256, 0, stream>>>(x, out + o_narr, uin);
        gemm(1, mkargs(uin, D_ + BN_, uW1, uw1R_h, uw1R_l, ub1, mlph, H_, D_ + BN_), H_, B_);
        gemm(0, mkargs(mlph, H_, uW2, uw2R_h, uw2R_l, ub2, out + o_unc, H_, H_), H_, B_);
        gemm(1, mkargs(out + o_narr, BN_, pW1, pw1R_h, pw1R_l, pb1, t1, H_, BN_), H_, B_);
        gemm(0, mkargs(t1, H_, pW2, pw2R_h, pw2R_l, pb2, out + o_pred, BN_, H_), BN_, B_);
        copy_f<<<(B_ * H_) / 256, 256, 0, stream>>>(hfin, out + o_lh);
        return;
    }

    // =============== legacy fallback (fp32-direct, any ws) ===============
    {
        GArgs g0 = mkargs(x, (long)W_ * D_, W_ih, 0, 0, b_ih, gibuf[0], G3, D_);
        hilo_gemm64<0, 0><<<dim3(48, 8), 256, 0, stream>>>(g0);
    }
    for (int w = 0; w < W_; ++w) {
        StepArgs s;
        s.h_in  = hbuf[w & 1];
        s.h_out = hbuf[(w + 1) & 1];
        s.W_hh = W_hh;
        s.gi = gibuf[w & 1];
        s.b_hh = b_hh;
        s.xw = (w + 1 < W_) ? (x + (long)(w + 1) * D_) : nullptr;
        s.W_ih = W_ih;
        s.b_ih = b_ih;
        s.gi_out = gibuf[(w + 1) & 1];
        gru_step2<<<640, 256, 0, stream>>>(s);
    }
    float* hfin = hbuf[0];

    auto gemmL = [&](int act, GArgs g, int N, int M) {
        dim3 grid(N / 64, M / 64);
        if (act == 1) hilo_gemm64<1, 0><<<grid, 256, 0, stream>>>(g);
        else          hilo_gemm64<0, 0><<<grid, 256, 0, stream>>>(g);
    };
    gemmL(0, mkargs(hfin, H_, Wq, 0, 0, bq, q, BN_, H_), BN_, B_);
    vq16<<<256, 256, 0, stream>>>(q, emb, e2, out + o_idx, idxi);
    gather_loss<<<(B_ * K_ * C_) / 256, 256, 0, stream>>>(
        q, emb, idxi, out + o_quant, out + o_narr, out + o_loss);
    build_uin<<<(B_ * (D_ + BN_)) / 256, 256, 0, stream>>>(x, out + o_narr, uin);
    gemmL(1, mkargs(uin, D_ + BN_, uW1, 0, 0, ub1, mlph, H_, D_ + BN_), H_, B_);
    gemmL(0, mkargs(mlph, H_, uW2, 0, 0, ub2, out + o_unc, H_, H_), H_, B_);
    gemmL(1, mkargs(out + o_narr, BN_, pW1, 0, 0, pb1, t1, H_, BN_), H_, B_);
    gemmL(0, mkargs(t1, H_, pW2, 0, 0, pb2, out + o_pred, BN_, H_), BN_, B_);
    copy_f<<<(B_ * H_) / 256, 256, 0, stream>>>(hfin, out + o_lh);
}